// Round 18
// baseline (115.594 us; speedup 1.0000x reference)
//
#include <hip/hip_runtime.h>

typedef __attribute__((ext_vector_type(4))) float f32x4;
typedef __attribute__((ext_vector_type(8))) short bf16x8;
typedef __attribute__((ext_vector_type(4))) int   i32x4;
typedef __attribute__((ext_vector_type(2))) int   i32x2;

#define B_ 2
#define S_ 2048
#define H_ 16
#define D_ 128
#define RS_ (H_ * D_)
#define LOG2E 1.44269504088896340736f
#define ZG 1.06f               // zeta - gamma
#define GM (-0.03f)            // gamma
#define QSC (0.08838834764831845f * LOG2E)   // 1/sqrt(128)*log2(e) folded into Q

__device__ __forceinline__ ushort f2bf(float x) {
    uint u = __builtin_bit_cast(uint, x);
    u += 0x7FFFu + ((u >> 16) & 1u);
    return (ushort)(u >> 16);
}

__device__ __forceinline__ void gld16(const void* g, void* l) {
    __builtin_amdgcn_global_load_lds(
        (const __attribute__((address_space(1))) unsigned int*)g,
        (__attribute__((address_space(3))) unsigned int*)l, 16, 0, 0);
}

// ---- fused prep: n<512 -> K fp32 -> bf16 [bh][s][d]; n>=512 -> V -> V^T tiles ----
__global__ __launch_bounds__(256)
void prep_kv(const float* __restrict__ Kg, const float* __restrict__ Vg,
             ushort* __restrict__ Kb, ushort* __restrict__ Vt)
{
    __shared__ ushort Vl[64 * 136];     // only used on the V path
    const int t = threadIdx.x;
    if (blockIdx.x < 512) {
        const int n  = blockIdx.x;      // K path: 512 blocks
        const int bh = n >> 4;
        const int ch = n & 15;
        const int s  = ch * 128 + (t >> 1);
        const int d0 = (t & 1) * 64;
        const int b  = bh >> 4, h = bh & 15;
        const float* in = Kg + (((size_t)b * S_ + s) * H_ + h) * D_ + d0;
        ushort* out = Kb + ((size_t)bh * S_ + s) * D_ + d0;
#pragma unroll
        for (int j = 0; j < 4; ++j) {
            f32x4 x0 = *(const f32x4*)(in + j * 16);
            f32x4 x1 = *(const f32x4*)(in + j * 16 + 4);
            f32x4 x2 = *(const f32x4*)(in + j * 16 + 8);
            f32x4 x3 = *(const f32x4*)(in + j * 16 + 12);
            union { ushort u[16]; i32x4 v[2]; } p;
#pragma unroll
            for (int i = 0; i < 4; ++i) {
                p.u[i]      = f2bf(x0[i]);
                p.u[4 + i]  = f2bf(x1[i]);
                p.u[8 + i]  = f2bf(x2[i]);
                p.u[12 + i] = f2bf(x3[i]);
            }
            *(i32x4*)(out + j * 16)     = p.v[0];
            *(i32x4*)(out + j * 16 + 8) = p.v[1];
        }
    } else {
        const int n  = blockIdx.x - 512;    // V path: 1024 blocks
        const int bh = n >> 5;
        const int kt = n & 31;
        const int b  = bh >> 4, h = bh & 15;
#pragma unroll
        for (int it = 0; it < 2; ++it) {
            const int r  = it * 32 + (t >> 3);
            const int c0 = (t & 7) * 16;
            const int s  = kt * 64 + r;
            const float* in = Vg + (((size_t)b * S_ + s) * H_ + h) * D_ + c0;
            f32x4 x0 = *(const f32x4*)(in);
            f32x4 x1 = *(const f32x4*)(in + 4);
            f32x4 x2 = *(const f32x4*)(in + 8);
            f32x4 x3 = *(const f32x4*)(in + 12);
            union { ushort u[16]; i32x4 v[2]; } p;
#pragma unroll
            for (int i = 0; i < 4; ++i) {
                p.u[i]      = f2bf(x0[i]);
                p.u[4 + i]  = f2bf(x1[i]);
                p.u[8 + i]  = f2bf(x2[i]);
                p.u[12 + i] = f2bf(x3[i]);
            }
            *(i32x4*)(Vl + r * 136 + c0)     = p.v[0];
            *(i32x4*)(Vl + r * 136 + c0 + 8) = p.v[1];
        }
        __syncthreads();
        const int d  = t >> 1;
        const int kh = (t & 1) * 32;
        ushort* out = Vt + ((size_t)bh * 32 + kt) * 8192 + d * 64 + kh;
        uint wds[16];
#pragma unroll
        for (int i = 0; i < 16; ++i) {
            uint a = Vl[(kh + 2 * i) * 136 + d];
            uint c = Vl[(kh + 2 * i + 1) * 136 + d];
            wds[i] = a | (c << 16);
        }
#pragma unroll
        for (int j = 0; j < 4; ++j)
            *(i32x4*)(out + j * 8) = *(i32x4*)&wds[j * 4];
    }
}

// ---- fused single-strip, swapped-QK, supertile-skip phase 2 ----
// Phase 1: each wave covers ALL 64 q-rows but only its 2 cc-slots (32 keys) of
// each 128-key supertile -> each kf LDS read feeds 4 MFMAs (4x fewer LDS reads).
// l-partials cross waves via Lpart LDS. Active-supertile mask is made
// BLOCK-UNIFORM via Flags[w] OR (per-wave masks differ: thr is per-row!).
__global__ __launch_bounds__(256, 3)
void attn_one(const float* __restrict__ Qg, const ushort* __restrict__ Kb,
              const ushort* __restrict__ Vt, float* __restrict__ Og)
{
    __shared__ char SHc[32768 + 4 * 2304 + 4096 + 1024 + 16];

    const int tid  = threadIdx.x;
    const int w    = tid >> 6;
    const int lane = tid & 63;
    const int g    = lane >> 4;
    const int l15  = lane & 15;
    char*  const Kl    = SHc;
    char*  const Vl    = SHc + 16384;
    char*  const pB    = SHc + 32768 + w * 2304;   // per-wave P [16 q][64 k], 144B rows
    float* const SmaxL = (float*)(SHc + 41984);    // [ww][st][l15]
    float* const Lpart = (float*)(SHc + 46080);    // [ww][qg][l15]
    uint*  const Flags = (uint*)(SHc + 47104);     // [ww]

    const int n  = blockIdx.x;                 // 1024 blocks
    const int qt = 31 - (n >> 5);              // big strips dispatch first (LPT)
    const int bh = n & 31;
    const int b  = bh >> 4, h = bh & 15;

    const int q0  = qt * 64;
    const int qw0 = q0 + w * 16;
    const int qme = qw0 + l15;                 // this lane's q row (phase 2)

    const float*  Qbh = Qg + ((size_t)b * S_ * H_ + h) * D_;
    const ushort* Kp  = Kb + (size_t)bh * S_ * D_;
    const ushort* Vp  = Vt + (size_t)bh * 32 * 8192;

    auto stageK2 = [&](int kt) {     // 32 KB: K rows kt*128..+127, full 16-slot swz
#pragma unroll
        for (int i = 0; i < 8; ++i) {
            const int u = (w * 8 + i) * 64 + lane;
            const int r = u >> 4, cc = u & 15;
            const ushort* src = Kp + (size_t)(kt * 128 + r) * 128 + ((cc ^ (r & 15)) * 8);
            gld16(src, SHc + (w * 8 + i) * 1024);
        }
    };
    auto stageKV = [&](int kt) {     // 16 KB K (16-slot swz) + 16 KB V^T (8-slot swz)
#pragma unroll
        for (int i = 0; i < 4; ++i) {
            const int u = (w * 4 + i) * 64 + lane;
            const int r = u >> 4, cc = u & 15;
            const ushort* src = Kp + (size_t)(kt * 64 + r) * 128 + ((cc ^ (r & 15)) * 8);
            gld16(src, Kl + (w * 4 + i) * 1024);
        }
        const ushort* tile = Vp + (size_t)kt * 8192;
#pragma unroll
        for (int i = 0; i < 4; ++i) {
            const int u = (w * 4 + i) * 64 + lane;
            const int r = u >> 3, cc = u & 7;
            const ushort* src = tile + r * 64 + ((cc ^ (r & 7)) * 8);
            gld16(src, Vl + (w * 4 + i) * 1024);
        }
    };

    // ---- prologue: stage first K2 tile, overlap Q-frag loads (ALL 64 rows) ----
    stageK2(0);

    bf16x8 qfA[4][4];   // [qg][db] — dead after phase 1
#pragma unroll
    for (int qg = 0; qg < 4; ++qg) {
        const float* qptr = Qbh + (size_t)(q0 + qg * 16 + l15) * RS_;
#pragma unroll
        for (int db = 0; db < 4; ++db) {
            const float* p = qptr + db * 32 + g * 8;
            f32x4 a = *(const f32x4*)p;
            f32x4 d = *(const f32x4*)(p + 4);
#pragma unroll
            for (int i = 0; i < 4; ++i) {
                qfA[qg][db][i]     = (short)f2bf(a[i] * QSC);
                qfA[qg][db][i + 4] = (short)f2bf(d[i] * QSC);
            }
        }
    }
    asm volatile("s_waitcnt vmcnt(0)" ::: "memory");
    __syncthreads();

    // ---- phase 1: l-sums, BK=128; wave owns cc-slots {2w, 2w+1} for all rows ----
    float acc[4] = {0.f, 0.f, 0.f, 0.f};
    const int cc0 = w * 2;
    const int kt1 = (q0 + 191) >> 7;
#pragma unroll 1
    for (int kt = 0; kt < kt1; ++kt) {
        const ushort* K2 = (const ushort*)SHc;
        f32x4 s[4][2];  // [qg][cc2] — all indices compile-time after unroll
#pragma unroll
        for (int qg = 0; qg < 4; ++qg)
#pragma unroll
            for (int c2 = 0; c2 < 2; ++c2) s[qg][c2] = (f32x4){0.f, 0.f, 0.f, 0.f};
        __builtin_amdgcn_s_setprio(1);
#pragma unroll
        for (int db = 0; db < 4; ++db) {
#pragma unroll
            for (int c2 = 0; c2 < 2; ++c2) {
                const int cc = cc0 + c2;
                bf16x8 kf = *(const bf16x8*)(K2 + (cc * 16 + l15) * 128 +
                                             (((db * 4 + g) ^ l15) * 8));
#pragma unroll
                for (int qg = 0; qg < 4; ++qg)
                    s[qg][c2] = __builtin_amdgcn_mfma_f32_16x16x32_bf16(kf, qfA[qg][db], s[qg][c2], 0, 0, 0);
            }
        }
        __builtin_amdgcn_s_setprio(0);

        float sm = -1e30f;
        if (kt == kt1 - 1) {        // diagonal supertile: causal mask
#pragma unroll
            for (int qg = 0; qg < 4; ++qg) {
                const int q = q0 + qg * 16 + l15;
#pragma unroll
                for (int c2 = 0; c2 < 2; ++c2) {
                    const int key0 = kt * 128 + (cc0 + c2) * 16 + g * 4;
#pragma unroll
                    for (int r = 0; r < 4; ++r) {
                        const bool ok = (key0 + r <= q);
                        const float e = exp2f(s[qg][c2][r]);
                        acc[qg] += ok ? e : 0.f;
                        sm = fmaxf(sm, ok ? s[qg][c2][r] : -1e30f);
                    }
                }
            }
        } else {
#pragma unroll
            for (int qg = 0; qg < 4; ++qg)
#pragma unroll
                for (int c2 = 0; c2 < 2; ++c2)
#pragma unroll
                    for (int r = 0; r < 4; ++r) {
                        acc[qg] += exp2f(s[qg][c2][r]);
                        sm = fmaxf(sm, s[qg][c2][r]);
                    }
        }
        // wave's supertile max (blurred over rows sharing l15; conservative vote)
        sm = fmaxf(sm, __shfl_xor(sm, 16));
        sm = fmaxf(sm, __shfl_xor(sm, 32));
        if (lane < 16) SmaxL[(w * 16 + kt) * 16 + l15] = sm;
        __syncthreads();
        if (kt + 1 < kt1) {
            stageK2(kt + 1);
            asm volatile("s_waitcnt vmcnt(0)" ::: "memory");
        }
        __syncthreads();
    }

    // ---- cross-wave l reduction ----
#pragma unroll
    for (int qg = 0; qg < 4; ++qg) {
        float t = acc[qg];
        t += __shfl_xor(t, 16);
        t += __shfl_xor(t, 32);
        if (lane < 16) Lpart[(w * 4 + qg) * 16 + l15] = t;
    }

    // reload own-row Q fragments for phase 2 (avoids runtime-indexed qfA[w])
    bf16x8 qf[4];
    {
        const float* qptr = Qbh + (size_t)qme * RS_;
#pragma unroll
        for (int db = 0; db < 4; ++db) {
            const float* p = qptr + db * 32 + g * 8;
            f32x4 a = *(const f32x4*)p;
            f32x4 d = *(const f32x4*)(p + 4);
#pragma unroll
            for (int i = 0; i < 4; ++i) {
                qf[db][i]     = (short)f2bf(a[i] * QSC);
                qf[db][i + 4] = (short)f2bf(d[i] * QSC);
            }
        }
    }
    __syncthreads();

    const float l = Lpart[(0 * 4 + w) * 16 + l15] + Lpart[(1 * 4 + w) * 16 + l15]
                  + Lpart[(2 * 4 + w) * 16 + l15] + Lpart[(3 * 4 + w) * 16 + l15];
    const float c1  = ZG / l;
    const float thr = log2f(-GM / c1);   // s <= thr  =>  p clips to exactly 0

    // per-wave vote (thr is PER-ROW, so masks differ across waves!)
    uint mymask = 0;
#pragma unroll 1
    for (int st = 0; st < kt1; ++st) {
        const float sm = fmaxf(fmaxf(SmaxL[(0 * 16 + st) * 16 + l15],
                                     SmaxL[(1 * 16 + st) * 16 + l15]),
                               fmaxf(SmaxL[(2 * 16 + st) * 16 + l15],
                                     SmaxL[(3 * 16 + st) * 16 + l15]));
        if (__any(sm > thr)) mymask |= (1u << st);
    }
    if (lane == 0) Flags[w] = mymask;
    __syncthreads();                     // also fences SmaxL/Lpart reads vs Kl reuse
    const uint blockmask = Flags[0] | Flags[1] | Flags[2] | Flags[3];

    const int kt2 = qt + 1;
    int kt = 0;
    while (kt < kt2 && !((blockmask >> (kt >> 1)) & 1u)) ++kt;
    if (kt < kt2) stageKV(kt);
    asm volatile("s_waitcnt vmcnt(0)" ::: "memory");
    __syncthreads();

    // ---- phase 2: only active supertiles; P = clip(c1*e+GM), O += P V ----
    f32x4 o[8];
#pragma unroll
    for (int db = 0; db < 8; ++db) o[db] = (f32x4){0.f, 0.f, 0.f, 0.f};

#pragma unroll 1
    while (kt < kt2) {
        f32x4 s[4];
#pragma unroll
        for (int cb = 0; cb < 4; ++cb) s[cb] = (f32x4){0.f, 0.f, 0.f, 0.f};
        __builtin_amdgcn_s_setprio(1);
#pragma unroll
        for (int db = 0; db < 4; ++db) {
            const int usw = ((db * 4 + g) ^ l15) * 8;
#pragma unroll
            for (int cb = 0; cb < 4; ++cb) {
                bf16x8 kf = *(const bf16x8*)((const ushort*)Kl + (cb * 16 + l15) * 128 + usw);
                s[cb] = __builtin_amdgcn_mfma_f32_16x16x32_bf16(kf, qf[db], s[cb], 0, 0, 0);
            }
        }
        __builtin_amdgcn_s_setprio(0);

        // per-64-tile vote (finer than the supertile mask)
        float smax = fmaxf(fmaxf(fmaxf(s[0][0], s[0][1]), fmaxf(s[0][2], s[0][3])),
                           fmaxf(fmaxf(s[1][0], s[1][1]), fmaxf(s[1][2], s[1][3])));
        smax = fmaxf(smax,
               fmaxf(fmaxf(fmaxf(s[2][0], s[2][1]), fmaxf(s[2][2], s[2][3])),
                     fmaxf(fmaxf(s[3][0], s[3][1]), fmaxf(s[3][2], s[3][3]))));

        if (__any(smax > thr)) {
            const bool diag = (kt == kt2 - 1);
#pragma unroll
            for (int cb = 0; cb < 4; ++cb) {
                const int key0 = kt * 64 + cb * 16 + g * 4;
                float p[4];
#pragma unroll
                for (int r = 0; r < 4; ++r) {
                    float e = exp2f(s[cb][r]);
                    if (diag) e = (key0 + r <= qme) ? e : 0.f;
                    p[r] = fminf(fmaxf(c1 * e + GM, 0.f), 1.f);
                }
                uint r01, r23;
                asm("v_cvt_pk_bf16_f32 %0, %1, %2" : "=v"(r01) : "v"(p[0]), "v"(p[1]));
                asm("v_cvt_pk_bf16_f32 %0, %1, %2" : "=v"(r23) : "v"(p[2]), "v"(p[3]));
                i32x2 pv2 = {(int)r01, (int)r23};
                *(i32x2*)(pB + l15 * 144 + cb * 32 + g * 8) = pv2;   // keys cb*16+g*4..+3
            }
            // in-wave: P writes must land before cross-lane P reads
            asm volatile("s_waitcnt lgkmcnt(0)" ::: "memory");
            f32x4 onew[8];
            __builtin_amdgcn_s_setprio(1);
#pragma unroll
            for (int ks = 0; ks < 2; ++ks) {
                bf16x8 pf = *(const bf16x8*)(pB + l15 * 144 + ks * 64 + g * 16);
#pragma unroll
                for (int db = 0; db < 8; ++db) {
                    const int d = db * 16 + l15;
                    bf16x8 vf = *(const bf16x8*)(Vl + d * 128 +
                                                 (((ks * 4 + g) ^ (d & 7)) * 16));
                    f32x4& dst = (ks == 0) ? onew[db] : o[db];
                    const f32x4 src = (ks == 0) ? o[db] : onew[db];
                    dst = __builtin_amdgcn_mfma_f32_16x16x32_bf16(pf, vf, src, 0, 0, 0);
                }
            }
            __builtin_amdgcn_s_setprio(0);
        }

        // advance to next active 64-tile (block-uniform)
        int nkt = kt + 1;
        while (nkt < kt2 && !((blockmask >> (nkt >> 1)) & 1u)) ++nkt;
        __syncthreads();
        if (nkt < kt2) {
            stageKV(nkt);
            asm volatile("s_waitcnt vmcnt(0)" ::: "memory");
        }
        __syncthreads();
        kt = nkt;
    }

    // ---- epilogue: fp32 out ----
    const size_t orow0 = ((size_t)(b * S_ + qw0) * H_ + h) * D_;
#pragma unroll
    for (int db = 0; db < 8; ++db) {
#pragma unroll
        for (int r = 0; r < 4; ++r) {
            const int qr = g * 4 + r;
            Og[orow0 + (size_t)qr * RS_ + db * 16 + l15] = o[db][r];
        }
    }
}

// ---------------- fallback (round-4, no workspace needed) ----------------
__global__ __launch_bounds__(256, 2)
void attn_fwd(const float* __restrict__ Qg, const float* __restrict__ Kg,
              const float* __restrict__ Vg, float* __restrict__ Og)
{
    __shared__ ushort Kl[32 * 128];
    __shared__ ushort Vt[128 * 40];
    __shared__ ushort Pl[4][16 * 40];

    const int tid  = threadIdx.x;
    const int w    = tid >> 6;
    const int lane = tid & 63;
    const int g    = lane >> 4;
    const int l15  = lane & 15;

    const int q0 = blockIdx.x * 64;
    const int bh = blockIdx.y;
    const int b  = bh >> 4;
    const int h  = bh & (H_ - 1);

    const size_t bh_off = ((size_t)b * S_ * H_ + h) * D_;
    const float* Qp = Qg + bh_off;
    const float* Kp = Kg + bh_off;
    const float* Vp = Vg + bh_off;

    const int qw0 = q0 + w * 16;
    const int wave_last_q = qw0 + 15;
    bf16x8 qf[4];
    {
        const float* qptr = Qp + (size_t)(qw0 + l15) * RS_;
        const float sc = 0.08838834764831845f;
#pragma unroll
        for (int db = 0; db < 4; ++db) {
            const float* p = qptr + db * 32 + g * 8;
            f32x4 a = *(const f32x4*)p;
            f32x4 c = *(const f32x4*)(p + 4);
#pragma unroll
            for (int i = 0; i < 4; ++i) {
                qf[db][i]     = (short)f2bf(a[i] * sc);
                qf[db][i + 4] = (short)f2bf(c[i] * sc);
            }
        }
    }

    char* const klB = (char*)Kl;
    char* const vtB = (char*)Vt;
    const int kr  = tid >> 3;
    const int kcu = (tid & 7) * 2;
    const int vk  = (tid >> 5) * 4;
    const int vd  = (tid & 31) * 4;

    auto stageK = [&](int kt0) {
        const float* p = Kp + (size_t)(kt0 + kr) * RS_ + kcu * 8;
        f32x4 x0 = *(const f32x4*)(p);
        f32x4 x1 = *(const f32x4*)(p + 4);
        f32x4 x2 = *(const f32x4*)(p + 8);
        f32x4 x3 = *(const f32x4*)(p + 12);
        union { ushort u[8]; i32x4 v; } a, c;
#pragma unroll
        for (int i = 0; i < 4; ++i) {
            a.u[i]     = f2bf(x0[i]);
            a.u[i + 4] = f2bf(x1[i]);
            c.u[i]     = f2bf(x2[i]);
            c.u[i + 4] = f2bf(x3[i]);
        }
        const int sw = kr & 7;
        *(i32x4*)(klB + kr * 256 + ((kcu ^ sw) * 16))       = a.v;
        *(i32x4*)(klB + kr * 256 + (((kcu + 1) ^ sw) * 16)) = c.v;
    };

    auto stageV = [&](int kt0) {
        ushort t[4][4];
#pragma unroll
        for (int i = 0; i < 4; ++i) {
            const f32x4 x = *(const f32x4*)(Vp + (size_t)(kt0 + vk + i) * RS_ + vd);
#pragma unroll
            for (int j = 0; j < 4; ++j) t[i][j] = f2bf(x[j]);
        }
#pragma unroll
        for (int j = 0; j < 4; ++j) {
            union { ushort u[4]; i32x2 v; } pk;
#pragma unroll
            for (int i = 0; i < 4; ++i) pk.u[i] = t[i][j];
            *(i32x2*)(vtB + (size_t)(vd + j) * 80 + vk * 2) = pk.v;
        }
    };

    auto qkTile = [&](f32x4& s0, f32x4& s1) {
        s0 = (f32x4){0.f, 0.f, 0.f, 0.f};
        s1 = (f32x4){0.f, 0.f, 0.f, 0.f};
        const int swz = l15 & 7;
#pragma unroll
        for (int db = 0; db < 4; ++db) {
            const int unit = db * 4 + g;
            bf16x8 k0 = *(const bf16x8*)(klB + l15 * 256 + ((unit ^ swz) * 16));
            bf16x8 k1 = *(const bf16x8*)(klB + (l15 + 16) * 256 + ((unit ^ swz) * 16));
            s0 = __builtin_amdgcn_mfma_f32_16x16x32_bf16(qf[db], k0, s0, 0, 0, 0);
            s1 = __builtin_amdgcn_mfma_f32_16x16x32_bf16(qf[db], k1, s1, 0, 0, 0);
        }
    };

    const int ktiles = (q0 + 64) / 32;

    float m[4] = {-1e30f, -1e30f, -1e30f, -1e30f};
    float l[4] = {0.f, 0.f, 0.f, 0.f};

    for (int kt = 0; kt < ktiles; ++kt) {
        const int kt0 = kt * 32;
        __syncthreads();
        stageK(kt0);
        __syncthreads();
        if (kt0 > wave_last_q) continue;
        f32x4 s0, s1;
        qkTile(s0, s1);
#pragma unroll
        for (int r = 0; r < 4; ++r) {
            const int qq = qw0 + g * 4 + r;
            const int ke = kt0 + l15;
            float v0 = (ke <= qq)      ? s0[r] : -1e30f;
            float v1 = (ke + 16 <= qq) ? s1[r] : -1e30f;
            float tmax = fmaxf(v0, v1);
            tmax = fmaxf(tmax, __shfl_xor(tmax, 1));
            tmax = fmaxf(tmax, __shfl_xor(tmax, 2));
            tmax = fmaxf(tmax, __shfl_xor(tmax, 4));
            tmax = fmaxf(tmax, __shfl_xor(tmax, 8));
            const float mn = fmaxf(m[r], tmax);
            float es = exp2f((v0 - mn) * LOG2E) + exp2f((v1 - mn) * LOG2E);
            es += __shfl_xor(es, 1);
            es += __shfl_xor(es, 2);
            es += __shfl_xor(es, 4);
            es += __shfl_xor(es, 8);
            l[r] = l[r] * exp2f((m[r] - mn) * LOG2E) + es;
            m[r] = mn;
        }
    }

    float c1[4];
#pragma unroll
    for (int r = 0; r < 4; ++r) c1[r] = ZG / l[r];

    f32x4 o[8];
#pragma unroll
    for (int db = 0; db < 8; ++db) o[db] = (f32x4){0.f, 0.f, 0.f, 0.f};

    char* const pB = (char*)(Pl[w]);

    for (int kt = 0; kt < ktiles; ++kt) {
        const int kt0 = kt * 32;
        __syncthreads();
        stageK(kt0);
        stageV(kt0);
        __syncthreads();
        if (kt0 > wave_last_q) continue;
        f32x4 s0, s1;
        qkTile(s0, s1);
#pragma unroll
        for (int r = 0; r < 4; ++r) {
            const int qq = qw0 + g * 4 + r;
            const int ke = kt0 + l15;
            float v0 = (ke <= qq)      ? s0[r] : -1e30f;
            float v1 = (ke + 16 <= qq) ? s1[r] : -1e30f;
            float p0 = c1[r] * exp2f((v0 - m[r]) * LOG2E) + GM;
            float p1 = c1[r] * exp2f((v1 - m[r]) * LOG2E) + GM;
            p0 = fminf(fmaxf(p0, 0.f), 1.f);
            p1 = fminf(fmaxf(p1, 0.f), 1.f);
            const int qr = g * 4 + r;
            *(ushort*)(pB + qr * 80 + l15 * 2)        = f2bf(p0);
            *(ushort*)(pB + qr * 80 + (l15 + 16) * 2) = f2bf(p1);
        }
        asm volatile("s_waitcnt lgkmcnt(0)" ::: "memory");
        bf16x8 pf = *(const bf16x8*)(pB + l15 * 80 + g * 16);
#pragma unroll
        for (int db = 0; db < 8; ++db) {
            bf16x8 vf = *(const bf16x8*)(vtB + (size_t)(db * 16 + l15) * 80 + g * 16);
            o[db] = __builtin_amdgcn_mfma_f32_16x16x32_bf16(pf, vf, o[db], 0, 0, 0);
        }
    }

    const size_t orow0 = ((size_t)(b * S_ + qw0) * H_ + h) * D_;
#pragma unroll
    for (int db = 0; db < 8; ++db) {
#pragma unroll
        for (int r = 0; r < 4; ++r) {
            const int qr = g * 4 + r;
            Og[orow0 + (size_t)qr * RS_ + db * 16 + l15] = o[db][r];
        }
    }
}

extern "C" void kernel_launch(void* const* d_in, const int* in_sizes, int n_in,
                              void* d_out, int out_size, void* d_ws, size_t ws_size,
                              hipStream_t stream)
{
    const float* Q = (const float*)d_in[0];
    const float* K = (const float*)d_in[1];
    const float* V = (const float*)d_in[2];
    (void)in_sizes; (void)n_in; (void)out_size;

    if (ws_size >= (size_t)33554432) {
        ushort* Kb = (ushort*)d_ws;
        ushort* Vt = (ushort*)d_ws + 8388608;   // +16 MB
        prep_kv<<<dim3(1536), dim3(256), 0, stream>>>(K, V, Kb, Vt);
        attn_one<<<dim3(1024), dim3(256), 0, stream>>>(Q, Kb, Vt, (float*)d_out);
    } else {
        attn_fwd<<<dim3(S_ / 64, B_ * H_), dim3(256), 0, stream>>>(Q, K, V, (float*)d_out);
    }
}

// Round 19
// 83.425 us; speedup vs baseline: 1.3856x; 1.3856x over previous
//
#include <hip/hip_runtime.h>

typedef __attribute__((ext_vector_type(4))) float f32x4;
typedef __attribute__((ext_vector_type(8))) short bf16x8;
typedef __attribute__((ext_vector_type(4))) int   i32x4;
typedef __attribute__((ext_vector_type(2))) int   i32x2;

#define B_ 2
#define S_ 2048
#define H_ 16
#define D_ 128
#define RS_ (H_ * D_)
#define LOG2E 1.44269504088896340736f
#define ZG 1.06f               // zeta - gamma
#define GM (-0.03f)            // gamma
#define QSC (0.08838834764831845f * LOG2E)   // 1/sqrt(128)*log2(e) folded into Q

__device__ __forceinline__ ushort f2bf(float x) {
    uint u = __builtin_bit_cast(uint, x);
    u += 0x7FFFu + ((u >> 16) & 1u);
    return (ushort)(u >> 16);
}

__device__ __forceinline__ void gld16(const void* g, void* l) {
    __builtin_amdgcn_global_load_lds(
        (const __attribute__((address_space(1))) unsigned int*)g,
        (__attribute__((address_space(3))) unsigned int*)l, 16, 0, 0);
}

// ---- fused prep: n<512 -> K fp32 -> bf16 [bh][s][d]; n>=512 -> V -> V^T tiles ----
__global__ __launch_bounds__(256)
void prep_kv(const float* __restrict__ Kg, const float* __restrict__ Vg,
             ushort* __restrict__ Kb, ushort* __restrict__ Vt)
{
    __shared__ ushort Vl[64 * 136];     // only used on the V path
    const int t = threadIdx.x;
    if (blockIdx.x < 512) {
        const int n  = blockIdx.x;      // K path: 512 blocks
        const int bh = n >> 4;
        const int ch = n & 15;
        const int s  = ch * 128 + (t >> 1);
        const int d0 = (t & 1) * 64;
        const int b  = bh >> 4, h = bh & 15;
        const float* in = Kg + (((size_t)b * S_ + s) * H_ + h) * D_ + d0;
        ushort* out = Kb + ((size_t)bh * S_ + s) * D_ + d0;
#pragma unroll
        for (int j = 0; j < 4; ++j) {
            f32x4 x0 = *(const f32x4*)(in + j * 16);
            f32x4 x1 = *(const f32x4*)(in + j * 16 + 4);
            f32x4 x2 = *(const f32x4*)(in + j * 16 + 8);
            f32x4 x3 = *(const f32x4*)(in + j * 16 + 12);
            union { ushort u[16]; i32x4 v[2]; } p;
#pragma unroll
            for (int i = 0; i < 4; ++i) {
                p.u[i]      = f2bf(x0[i]);
                p.u[4 + i]  = f2bf(x1[i]);
                p.u[8 + i]  = f2bf(x2[i]);
                p.u[12 + i] = f2bf(x3[i]);
            }
            *(i32x4*)(out + j * 16)     = p.v[0];
            *(i32x4*)(out + j * 16 + 8) = p.v[1];
        }
    } else {
        const int n  = blockIdx.x - 512;    // V path: 1024 blocks
        const int bh = n >> 5;
        const int kt = n & 31;
        const int b  = bh >> 4, h = bh & 15;
#pragma unroll
        for (int it = 0; it < 2; ++it) {
            const int r  = it * 32 + (t >> 3);
            const int c0 = (t & 7) * 16;
            const int s  = kt * 64 + r;
            const float* in = Vg + (((size_t)b * S_ + s) * H_ + h) * D_ + c0;
            f32x4 x0 = *(const f32x4*)(in);
            f32x4 x1 = *(const f32x4*)(in + 4);
            f32x4 x2 = *(const f32x4*)(in + 8);
            f32x4 x3 = *(const f32x4*)(in + 12);
            union { ushort u[16]; i32x4 v[2]; } p;
#pragma unroll
            for (int i = 0; i < 4; ++i) {
                p.u[i]      = f2bf(x0[i]);
                p.u[4 + i]  = f2bf(x1[i]);
                p.u[8 + i]  = f2bf(x2[i]);
                p.u[12 + i] = f2bf(x3[i]);
            }
            *(i32x4*)(Vl + r * 136 + c0)     = p.v[0];
            *(i32x4*)(Vl + r * 136 + c0 + 8) = p.v[1];
        }
        __syncthreads();
        const int d  = t >> 1;
        const int kh = (t & 1) * 32;
        ushort* out = Vt + ((size_t)bh * 32 + kt) * 8192 + d * 64 + kh;
        uint wds[16];
#pragma unroll
        for (int i = 0; i < 16; ++i) {
            uint a = Vl[(kh + 2 * i) * 136 + d];
            uint c = Vl[(kh + 2 * i + 1) * 136 + d];
            wds[i] = a | (c << 16);
        }
#pragma unroll
        for (int j = 0; j < 4; ++j)
            *(i32x4*)(out + j * 8) = *(i32x4*)&wds[j * 4];
    }
}

// ---- fused single-strip, swapped-QK, supertile-skip phase 2 (round-16 best) ----
// Phase 1 records per-row (l15) masked score max per 128-key supertile in LDS.
// After c1/thr known, waves vote per supertile; 4 wave masks OR -> block-uniform
// bitmask; phase 2 stages+computes ONLY active supertiles (exact: skipped tiles'
// P would clip to 0; phase-2 scores are bitwise identical to phase-1's).
__global__ __launch_bounds__(256, 3)
void attn_one(const float* __restrict__ Qg, const ushort* __restrict__ Kb,
              const ushort* __restrict__ Vt, float* __restrict__ Og)
{
    __shared__ char SHc[32768 + 4 * 2304 + 4096 + 16];

    const int tid  = threadIdx.x;
    const int w    = tid >> 6;
    const int lane = tid & 63;
    const int g    = lane >> 4;
    const int l15  = lane & 15;
    char*  const Kl    = SHc;
    char*  const Vl    = SHc + 16384;
    char*  const pB    = SHc + 32768 + w * 2304;   // per-wave P [16 q][64 k], 144B rows
    float* const SmaxL = (float*)(SHc + 41984);    // [w][st][l15]
    uint*  const Flags = (uint*)(SHc + 46080);     // [w]

    const int n  = blockIdx.x;                 // 1024 blocks
    const int qt = 31 - (n >> 5);              // big strips dispatch first (LPT)
    const int bh = n & 31;
    const int b  = bh >> 4, h = bh & 15;

    const int q0  = qt * 64;
    const int qw0 = q0 + w * 16;
    const int qme = qw0 + l15;                 // this lane's q row

    const float*  Qbh = Qg + ((size_t)b * S_ * H_ + h) * D_;
    const ushort* Kp  = Kb + (size_t)bh * S_ * D_;
    const ushort* Vp  = Vt + (size_t)bh * 32 * 8192;

    auto stageK2 = [&](int kt) {     // 32 KB: K rows kt*128..+127, full 16-slot swz
#pragma unroll
        for (int i = 0; i < 8; ++i) {
            const int u = (w * 8 + i) * 64 + lane;
            const int r = u >> 4, cc = u & 15;
            const ushort* src = Kp + (size_t)(kt * 128 + r) * 128 + ((cc ^ (r & 15)) * 8);
            gld16(src, SHc + (w * 8 + i) * 1024);
        }
    };
    auto stageKV = [&](int kt) {     // 16 KB K (16-slot swz) + 16 KB V^T (8-slot swz)
#pragma unroll
        for (int i = 0; i < 4; ++i) {
            const int u = (w * 4 + i) * 64 + lane;
            const int r = u >> 4, cc = u & 15;
            const ushort* src = Kp + (size_t)(kt * 64 + r) * 128 + ((cc ^ (r & 15)) * 8);
            gld16(src, Kl + (w * 4 + i) * 1024);
        }
        const ushort* tile = Vp + (size_t)kt * 8192;
#pragma unroll
        for (int i = 0; i < 4; ++i) {
            const int u = (w * 4 + i) * 64 + lane;
            const int r = u >> 3, cc = u & 7;
            const ushort* src = tile + r * 64 + ((cc ^ (r & 7)) * 8);
            gld16(src, Vl + (w * 4 + i) * 1024);
        }
    };

    // ---- prologue: stage first K2 tile, overlap Q-frag loads ----
    stageK2(0);

    bf16x8 qf[4];
    {
        const float* qptr = Qbh + (size_t)qme * RS_;
#pragma unroll
        for (int db = 0; db < 4; ++db) {
            const float* p = qptr + db * 32 + g * 8;
            f32x4 a = *(const f32x4*)p;
            f32x4 d = *(const f32x4*)(p + 4);
#pragma unroll
            for (int i = 0; i < 4; ++i) {
                qf[db][i]     = (short)f2bf(a[i] * QSC);
                qf[db][i + 4] = (short)f2bf(d[i] * QSC);
            }
        }
    }
    asm volatile("s_waitcnt vmcnt(0)" ::: "memory");
    __syncthreads();

    // ---- phase 1: l-sums + per-supertile row maxima, BK=128 ----
    float acc = 0.f;
    const int kt1 = (q0 + 191) >> 7;
#pragma unroll 1
    for (int kt = 0; kt < kt1; ++kt) {
        const ushort* K2 = (const ushort*)SHc;
        f32x4 s[8];
#pragma unroll
        for (int cc = 0; cc < 8; ++cc) s[cc] = (f32x4){0.f, 0.f, 0.f, 0.f};
        __builtin_amdgcn_s_setprio(1);
#pragma unroll
        for (int db = 0; db < 4; ++db) {
            const int usw = ((db * 4 + g) ^ l15) * 8;
#pragma unroll
            for (int cc = 0; cc < 8; ++cc) {
                bf16x8 kf = *(const bf16x8*)(K2 + (cc * 16 + l15) * 128 + usw);
                s[cc] = __builtin_amdgcn_mfma_f32_16x16x32_bf16(kf, qf[db], s[cc], 0, 0, 0);
            }
        }
        __builtin_amdgcn_s_setprio(0);
        float sm = -1e30f;
        if (kt == kt1 - 1) {        // diagonal supertile: causal mask
#pragma unroll
            for (int cc = 0; cc < 8; ++cc) {
                const int key0 = kt * 128 + cc * 16 + g * 4;
#pragma unroll
                for (int r = 0; r < 4; ++r) {
                    const bool ok = (key0 + r <= qme);
                    const float e = exp2f(s[cc][r]);
                    acc += ok ? e : 0.f;
                    sm = fmaxf(sm, ok ? s[cc][r] : -1e30f);
                }
            }
        } else {
#pragma unroll
            for (int cc = 0; cc < 8; ++cc)
#pragma unroll
                for (int r = 0; r < 4; ++r) {
                    acc += exp2f(s[cc][r]);
                    sm = fmaxf(sm, s[cc][r]);
                }
        }
        // reduce row max over the 4 g-groups; lanes 0..15 store
        sm = fmaxf(sm, __shfl_xor(sm, 16));
        sm = fmaxf(sm, __shfl_xor(sm, 32));
        if (lane < 16) SmaxL[(w * 16 + kt) * 16 + l15] = sm;
        __syncthreads();
        if (kt + 1 < kt1) {
            stageK2(kt + 1);
            asm volatile("s_waitcnt vmcnt(0)" ::: "memory");
        }
        __syncthreads();
    }

    // ---- l-reduction, threshold, block-uniform active-supertile mask ----
    float c1;
    {
        float t = acc;
        t += __shfl_xor(t, 16);
        t += __shfl_xor(t, 32);
        c1 = ZG / t;
    }
    const float thr = log2f(-GM / c1);   // s <= thr  =>  p clips to exactly 0

    uint mymask = 0;
#pragma unroll 1
    for (int st = 0; st < kt1; ++st) {
        const float sm = SmaxL[(w * 16 + st) * 16 + l15];
        if (__any(sm > thr)) mymask |= (1u << st);
    }
    if (lane == 0) Flags[w] = mymask;
    __syncthreads();
    const uint blockmask = Flags[0] | Flags[1] | Flags[2] | Flags[3];

    const int kt2 = qt + 1;
    int kt = 0;
    while (kt < kt2 && !((blockmask >> (kt >> 1)) & 1u)) ++kt;
    if (kt < kt2) stageKV(kt);
    asm volatile("s_waitcnt vmcnt(0)" ::: "memory");
    __syncthreads();

    // ---- phase 2: only active supertiles; P = clip(c1*e+GM), O += P V ----
    f32x4 o[8];
#pragma unroll
    for (int db = 0; db < 8; ++db) o[db] = (f32x4){0.f, 0.f, 0.f, 0.f};

#pragma unroll 1
    while (kt < kt2) {
        f32x4 s[4];
#pragma unroll
        for (int cb = 0; cb < 4; ++cb) s[cb] = (f32x4){0.f, 0.f, 0.f, 0.f};
        __builtin_amdgcn_s_setprio(1);
#pragma unroll
        for (int db = 0; db < 4; ++db) {
            const int usw = ((db * 4 + g) ^ l15) * 8;
#pragma unroll
            for (int cb = 0; cb < 4; ++cb) {
                bf16x8 kf = *(const bf16x8*)((const ushort*)Kl + (cb * 16 + l15) * 128 + usw);
                s[cb] = __builtin_amdgcn_mfma_f32_16x16x32_bf16(kf, qf[db], s[cb], 0, 0, 0);
            }
        }
        __builtin_amdgcn_s_setprio(0);

        // per-64-tile vote (finer than the supertile mask)
        float smax = fmaxf(fmaxf(fmaxf(s[0][0], s[0][1]), fmaxf(s[0][2], s[0][3])),
                           fmaxf(fmaxf(s[1][0], s[1][1]), fmaxf(s[1][2], s[1][3])));
        smax = fmaxf(smax,
               fmaxf(fmaxf(fmaxf(s[2][0], s[2][1]), fmaxf(s[2][2], s[2][3])),
                     fmaxf(fmaxf(s[3][0], s[3][1]), fmaxf(s[3][2], s[3][3]))));

        if (__any(smax > thr)) {
            const bool diag = (kt == kt2 - 1);
#pragma unroll
            for (int cb = 0; cb < 4; ++cb) {
                const int key0 = kt * 64 + cb * 16 + g * 4;
                float p[4];
#pragma unroll
                for (int r = 0; r < 4; ++r) {
                    float e = exp2f(s[cb][r]);
                    if (diag) e = (key0 + r <= qme) ? e : 0.f;
                    p[r] = fminf(fmaxf(c1 * e + GM, 0.f), 1.f);
                }
                uint r01, r23;
                asm("v_cvt_pk_bf16_f32 %0, %1, %2" : "=v"(r01) : "v"(p[0]), "v"(p[1]));
                asm("v_cvt_pk_bf16_f32 %0, %1, %2" : "=v"(r23) : "v"(p[2]), "v"(p[3]));
                i32x2 pv2 = {(int)r01, (int)r23};
                *(i32x2*)(pB + l15 * 144 + cb * 32 + g * 8) = pv2;   // keys cb*16+g*4..+3
            }
            // in-wave: P writes must land before cross-lane P reads
            asm volatile("s_waitcnt lgkmcnt(0)" ::: "memory");
            f32x4 onew[8];
            __builtin_amdgcn_s_setprio(1);
#pragma unroll
            for (int ks = 0; ks < 2; ++ks) {
                bf16x8 pf = *(const bf16x8*)(pB + l15 * 144 + ks * 64 + g * 16);
#pragma unroll
                for (int db = 0; db < 8; ++db) {
                    const int d = db * 16 + l15;
                    bf16x8 vf = *(const bf16x8*)(Vl + d * 128 +
                                                 (((ks * 4 + g) ^ (d & 7)) * 16));
                    f32x4& dst = (ks == 0) ? onew[db] : o[db];
                    const f32x4 src = (ks == 0) ? o[db] : onew[db];
                    dst = __builtin_amdgcn_mfma_f32_16x16x32_bf16(pf, vf, src, 0, 0, 0);
                }
            }
            __builtin_amdgcn_s_setprio(0);
        }

        // advance to next active 64-tile (block-uniform)
        int nkt = kt + 1;
        while (nkt < kt2 && !((blockmask >> (nkt >> 1)) & 1u)) ++nkt;
        __syncthreads();
        if (nkt < kt2) {
            stageKV(nkt);
            asm volatile("s_waitcnt vmcnt(0)" ::: "memory");
        }
        __syncthreads();
        kt = nkt;
    }

    // ---- epilogue: fp32 out ----
    const size_t orow0 = ((size_t)(b * S_ + qw0) * H_ + h) * D_;
#pragma unroll
    for (int db = 0; db < 8; ++db) {
#pragma unroll
        for (int r = 0; r < 4; ++r) {
            const int qr = g * 4 + r;
            Og[orow0 + (size_t)qr * RS_ + db * 16 + l15] = o[db][r];
        }
    }
}

// ---------------- fallback (round-4, no workspace needed) ----------------
__global__ __launch_bounds__(256, 2)
void attn_fwd(const float* __restrict__ Qg, const float* __restrict__ Kg,
              const float* __restrict__ Vg, float* __restrict__ Og)
{
    __shared__ ushort Kl[32 * 128];
    __shared__ ushort Vt[128 * 40];
    __shared__ ushort Pl[4][16 * 40];

    const int tid  = threadIdx.x;
    const int w    = tid >> 6;
    const int lane = tid & 63;
    const int g    = lane >> 4;
    const int l15  = lane & 15;

    const int q0 = blockIdx.x * 64;
    const int bh = blockIdx.y;
    const int b  = bh >> 4;
    const int h  = bh & (H_ - 1);

    const size_t bh_off = ((size_t)b * S_ * H_ + h) * D_;
    const float* Qp = Qg + bh_off;
    const float* Kp = Kg + bh_off;
    const float* Vp = Vg + bh_off;

    const int qw0 = q0 + w * 16;
    const int wave_last_q = qw0 + 15;
    bf16x8 qf[4];
    {
        const float* qptr = Qp + (size_t)(qw0 + l15) * RS_;
        const float sc = 0.08838834764831845f;
#pragma unroll
        for (int db = 0; db < 4; ++db) {
            const float* p = qptr + db * 32 + g * 8;
            f32x4 a = *(const f32x4*)p;
            f32x4 c = *(const f32x4*)(p + 4);
#pragma unroll
            for (int i = 0; i < 4; ++i) {
                qf[db][i]     = (short)f2bf(a[i] * sc);
                qf[db][i + 4] = (short)f2bf(c[i] * sc);
            }
        }
    }

    char* const klB = (char*)Kl;
    char* const vtB = (char*)Vt;
    const int kr  = tid >> 3;
    const int kcu = (tid & 7) * 2;
    const int vk  = (tid >> 5) * 4;
    const int vd  = (tid & 31) * 4;

    auto stageK = [&](int kt0) {
        const float* p = Kp + (size_t)(kt0 + kr) * RS_ + kcu * 8;
        f32x4 x0 = *(const f32x4*)(p);
        f32x4 x1 = *(const f32x4*)(p + 4);
        f32x4 x2 = *(const f32x4*)(p + 8);
        f32x4 x3 = *(const f32x4*)(p + 12);
        union { ushort u[8]; i32x4 v; } a, c;
#pragma unroll
        for (int i = 0; i < 4; ++i) {
            a.u[i]     = f2bf(x0[i]);
            a.u[i + 4] = f2bf(x1[i]);
            c.u[i]     = f2bf(x2[i]);
            c.u[i + 4] = f2bf(x3[i]);
        }
        const int sw = kr & 7;
        *(i32x4*)(klB + kr * 256 + ((kcu ^ sw) * 16))       = a.v;
        *(i32x4*)(klB + kr * 256 + (((kcu + 1) ^ sw) * 16)) = c.v;
    };

    auto stageV = [&](int kt0) {
        ushort t[4][4];
#pragma unroll
        for (int i = 0; i < 4; ++i) {
            const f32x4 x = *(const f32x4*)(Vp + (size_t)(kt0 + vk + i) * RS_ + vd);
#pragma unroll
            for (int j = 0; j < 4; ++j) t[i][j] = f2bf(x[j]);
        }
#pragma unroll
        for (int j = 0; j < 4; ++j) {
            union { ushort u[4]; i32x2 v; } pk;
#pragma unroll
            for (int i = 0; i < 4; ++i) pk.u[i] = t[i][j];
            *(i32x2*)(vtB + (size_t)(vd + j) * 80 + vk * 2) = pk.v;
        }
    };

    auto qkTile = [&](f32x4& s0, f32x4& s1) {
        s0 = (f32x4){0.f, 0.f, 0.f, 0.f};
        s1 = (f32x4){0.f, 0.f, 0.f, 0.f};
        const int swz = l15 & 7;
#pragma unroll
        for (int db = 0; db < 4; ++db) {
            const int unit = db * 4 + g;
            bf16x8 k0 = *(const bf16x8*)(klB + l15 * 256 + ((unit ^ swz) * 16));
            bf16x8 k1 = *(const bf16x8*)(klB + (l15 + 16) * 256 + ((unit ^ swz) * 16));
            s0 = __builtin_amdgcn_mfma_f32_16x16x32_bf16(qf[db], k0, s0, 0, 0, 0);
            s1 = __builtin_amdgcn_mfma_f32_16x16x32_bf16(qf[db], k1, s1, 0, 0, 0);
        }
    };

    const int ktiles = (q0 + 64) / 32;

    float m[4] = {-1e30f, -1e30f, -1e30f, -1e30f};
    float l[4] = {0.f, 0.f, 0.f, 0.f};

    for (int kt = 0; kt < ktiles; ++kt) {
        const int kt0 = kt * 32;
        __syncthreads();
        stageK(kt0);
        __syncthreads();
        if (kt0 > wave_last_q) continue;
        f32x4 s0, s1;
        qkTile(s0, s1);
#pragma unroll
        for (int r = 0; r < 4; ++r) {
            const int qq = qw0 + g * 4 + r;
            const int ke = kt0 + l15;
            float v0 = (ke <= qq)      ? s0[r] : -1e30f;
            float v1 = (ke + 16 <= qq) ? s1[r] : -1e30f;
            float tmax = fmaxf(v0, v1);
            tmax = fmaxf(tmax, __shfl_xor(tmax, 1));
            tmax = fmaxf(tmax, __shfl_xor(tmax, 2));
            tmax = fmaxf(tmax, __shfl_xor(tmax, 4));
            tmax = fmaxf(tmax, __shfl_xor(tmax, 8));
            const float mn = fmaxf(m[r], tmax);
            float es = exp2f((v0 - mn) * LOG2E) + exp2f((v1 - mn) * LOG2E);
            es += __shfl_xor(es, 1);
            es += __shfl_xor(es, 2);
            es += __shfl_xor(es, 4);
            es += __shfl_xor(es, 8);
            l[r] = l[r] * exp2f((m[r] - mn) * LOG2E) + es;
            m[r] = mn;
        }
    }

    float c1[4];
#pragma unroll
    for (int r = 0; r < 4; ++r) c1[r] = ZG / l[r];

    f32x4 o[8];
#pragma unroll
    for (int db = 0; db < 8; ++db) o[db] = (f32x4){0.f, 0.f, 0.f, 0.f};

    char* const pB = (char*)(Pl[w]);

    for (int kt = 0; kt < ktiles; ++kt) {
        const int kt0 = kt * 32;
        __syncthreads();
        stageK(kt0);
        stageV(kt0);
        __syncthreads();
        if (kt0 > wave_last_q) continue;
        f32x4 s0, s1;
        qkTile(s0, s1);
#pragma unroll
        for (int r = 0; r < 4; ++r) {
            const int qq = qw0 + g * 4 + r;
            const int ke = kt0 + l15;
            float v0 = (ke <= qq)      ? s0[r] : -1e30f;
            float v1 = (ke + 16 <= qq) ? s1[r] : -1e30f;
            float p0 = c1[r] * exp2f((v0 - m[r]) * LOG2E) + GM;
            float p1 = c1[r] * exp2f((v1 - m[r]) * LOG2E) + GM;
            p0 = fminf(fmaxf(p0, 0.f), 1.f);
            p1 = fminf(fmaxf(p1, 0.f), 1.f);
            const int qr = g * 4 + r;
            *(ushort*)(pB + qr * 80 + l15 * 2)        = f2bf(p0);
            *(ushort*)(pB + qr * 80 + (l15 + 16) * 2) = f2bf(p1);
        }
        asm volatile("s_waitcnt lgkmcnt(0)" ::: "memory");
        bf16x8 pf = *(const bf16x8*)(pB + l15 * 80 + g * 16);
#pragma unroll
        for (int db = 0; db < 8; ++db) {
            bf16x8 vf = *(const bf16x8*)(vtB + (size_t)(db * 16 + l15) * 80 + g * 16);
            o[db] = __builtin_amdgcn_mfma_f32_16x16x32_bf16(pf, vf, o[db], 0, 0, 0);
        }
    }

    const size_t orow0 = ((size_t)(b * S_ + qw0) * H_ + h) * D_;
#pragma unroll
    for (int db = 0; db < 8; ++db) {
#pragma unroll
        for (int r = 0; r < 4; ++r) {
            const int qr = g * 4 + r;
            Og[orow0 + (size_t)qr * RS_ + db * 16 + l15] = o[db][r];
        }
    }
}

extern "C" void kernel_launch(void* const* d_in, const int* in_sizes, int n_in,
                              void* d_out, int out_size, void* d_ws, size_t ws_size,
                              hipStream_t stream)
{
    const float* Q = (const float*)d_in[0];
    const float* K = (const float*)d_in[1];
    const float* V = (const float*)d_in[2];
    (void)in_sizes; (void)n_in; (void)out_size;

    if (ws_size >= (size_t)33554432) {
        ushort* Kb = (ushort*)d_ws;
        ushort* Vt = (ushort*)d_ws + 8388608;   // +16 MB
        prep_kv<<<dim3(1536), dim3(256), 0, stream>>>(K, V, Kb, Vt);
        attn_one<<<dim3(1024), dim3(256), 0, stream>>>(Q, Kb, Vt, (float*)d_out);
    } else {
        attn_fwd<<<dim3(S_ / 64, B_ * H_), dim3(256), 0, stream>>>(Q, K, V, (float*)d_out);
    }
}

// Round 20
// 83.275 us; speedup vs baseline: 1.3881x; 1.0018x over previous
//
#include <hip/hip_runtime.h>

typedef __attribute__((ext_vector_type(4))) float f32x4;
typedef __attribute__((ext_vector_type(8))) short bf16x8;
typedef __attribute__((ext_vector_type(4))) int   i32x4;
typedef __attribute__((ext_vector_type(2))) int   i32x2;

#define B_ 2
#define S_ 2048
#define H_ 16
#define D_ 128
#define RS_ (H_ * D_)
#define LOG2E 1.44269504088896340736f
#define ZG 1.06f               // zeta - gamma
#define GM (-0.03f)            // gamma
#define QSC (0.08838834764831845f * LOG2E)   // 1/sqrt(128)*log2(e) folded into Q

__device__ __forceinline__ ushort f2bf(float x) {
    uint u = __builtin_bit_cast(uint, x);
    u += 0x7FFFu + ((u >> 16) & 1u);
    return (ushort)(u >> 16);
}

__device__ __forceinline__ void gld16(const void* g, void* l) {
    __builtin_amdgcn_global_load_lds(
        (const __attribute__((address_space(1))) unsigned int*)g,
        (__attribute__((address_space(3))) unsigned int*)l, 16, 0, 0);
}

// ---- fused prep: n<512 -> K fp32 -> bf16 [bh][s][d]; n>=512 -> V -> V^T tiles ----
__global__ __launch_bounds__(256)
void prep_kv(const float* __restrict__ Kg, const float* __restrict__ Vg,
             ushort* __restrict__ Kb, ushort* __restrict__ Vt)
{
    __shared__ ushort Vl[64 * 136];     // only used on the V path
    const int t = threadIdx.x;
    if (blockIdx.x < 512) {
        const int n  = blockIdx.x;      // K path: 512 blocks
        const int bh = n >> 4;
        const int ch = n & 15;
        const int s  = ch * 128 + (t >> 1);
        const int d0 = (t & 1) * 64;
        const int b  = bh >> 4, h = bh & 15;
        const float* in = Kg + (((size_t)b * S_ + s) * H_ + h) * D_ + d0;
        ushort* out = Kb + ((size_t)bh * S_ + s) * D_ + d0;
#pragma unroll
        for (int j = 0; j < 4; ++j) {
            f32x4 x0 = *(const f32x4*)(in + j * 16);
            f32x4 x1 = *(const f32x4*)(in + j * 16 + 4);
            f32x4 x2 = *(const f32x4*)(in + j * 16 + 8);
            f32x4 x3 = *(const f32x4*)(in + j * 16 + 12);
            union { ushort u[16]; i32x4 v[2]; } p;
#pragma unroll
            for (int i = 0; i < 4; ++i) {
                p.u[i]      = f2bf(x0[i]);
                p.u[4 + i]  = f2bf(x1[i]);
                p.u[8 + i]  = f2bf(x2[i]);
                p.u[12 + i] = f2bf(x3[i]);
            }
            *(i32x4*)(out + j * 16)     = p.v[0];
            *(i32x4*)(out + j * 16 + 8) = p.v[1];
        }
    } else {
        const int n  = blockIdx.x - 512;    // V path: 1024 blocks
        const int bh = n >> 5;
        const int kt = n & 31;
        const int b  = bh >> 4, h = bh & 15;
#pragma unroll
        for (int it = 0; it < 2; ++it) {
            const int r  = it * 32 + (t >> 3);
            const int c0 = (t & 7) * 16;
            const int s  = kt * 64 + r;
            const float* in = Vg + (((size_t)b * S_ + s) * H_ + h) * D_ + c0;
            f32x4 x0 = *(const f32x4*)(in);
            f32x4 x1 = *(const f32x4*)(in + 4);
            f32x4 x2 = *(const f32x4*)(in + 8);
            f32x4 x3 = *(const f32x4*)(in + 12);
            union { ushort u[16]; i32x4 v[2]; } p;
#pragma unroll
            for (int i = 0; i < 4; ++i) {
                p.u[i]      = f2bf(x0[i]);
                p.u[4 + i]  = f2bf(x1[i]);
                p.u[8 + i]  = f2bf(x2[i]);
                p.u[12 + i] = f2bf(x3[i]);
            }
            *(i32x4*)(Vl + r * 136 + c0)     = p.v[0];
            *(i32x4*)(Vl + r * 136 + c0 + 8) = p.v[1];
        }
        __syncthreads();
        const int d  = t >> 1;
        const int kh = (t & 1) * 32;
        ushort* out = Vt + ((size_t)bh * 32 + kt) * 8192 + d * 64 + kh;
        uint wds[16];
#pragma unroll
        for (int i = 0; i < 16; ++i) {
            uint a = Vl[(kh + 2 * i) * 136 + d];
            uint c = Vl[(kh + 2 * i + 1) * 136 + d];
            wds[i] = a | (c << 16);
        }
#pragma unroll
        for (int j = 0; j < 4; ++j)
            *(i32x4*)(out + j * 8) = *(i32x4*)&wds[j * 4];
    }
}

// ---- fused single-strip, swapped-QK, fine-grained tile-skip phase 2 ----
// Phase 1: BK=64, K double-buffered in the two 16KB halves (stage(kt+1) issued
// BEFORE compute(kt) -> staging latency hidden under MFMA+exp). Per-64-tile row
// maxima recorded in SmaxL; vote after c1/thr -> block-uniform 64-granular mask
// (Flags OR across waves); phase 2 stages+computes ONLY active 64-tiles.
__global__ __launch_bounds__(256, 3)
void attn_one(const float* __restrict__ Qg, const ushort* __restrict__ Kb,
              const ushort* __restrict__ Vt, float* __restrict__ Og)
{
    __shared__ char SHc[32768 + 4 * 2304 + 8192 + 16];

    const int tid  = threadIdx.x;
    const int w    = tid >> 6;
    const int lane = tid & 63;
    const int g    = lane >> 4;
    const int l15  = lane & 15;
    char*  const Kl    = SHc;                      // phase2 K / phase1 buf0
    char*  const Vl    = SHc + 16384;              // phase2 V / phase1 buf1
    char*  const pB    = SHc + 32768 + w * 2304;   // per-wave P [16 q][64 k], 144B rows
    float* const SmaxL = (float*)(SHc + 41984);    // [w][kt(0..31)][l15]
    uint*  const Flags = (uint*)(SHc + 50176);     // [w]

    const int n  = blockIdx.x;                 // 1024 blocks
    const int qt = 31 - (n >> 5);              // big strips dispatch first (LPT)
    const int bh = n & 31;
    const int b  = bh >> 4, h = bh & 15;

    const int q0  = qt * 64;
    const int qw0 = q0 + w * 16;
    const int qme = qw0 + l15;                 // this lane's q row

    const float*  Qbh = Qg + ((size_t)b * S_ * H_ + h) * D_;
    const ushort* Kp  = Kb + (size_t)bh * S_ * D_;
    const ushort* Vp  = Vt + (size_t)bh * 32 * 8192;

    auto stageK64 = [&](int kt, int bset) {  // 16 KB: K rows kt*64..+63, 16-slot swz
#pragma unroll
        for (int i = 0; i < 4; ++i) {
            const int u = (w * 4 + i) * 64 + lane;
            const int r = u >> 4, cc = u & 15;
            const ushort* src = Kp + (size_t)(kt * 64 + r) * 128 + ((cc ^ (r & 15)) * 8);
            gld16(src, SHc + bset * 16384 + (w * 4 + i) * 1024);
        }
    };
    auto stageKV = [&](int kt) {     // 16 KB K (16-slot swz) + 16 KB V^T (8-slot swz)
#pragma unroll
        for (int i = 0; i < 4; ++i) {
            const int u = (w * 4 + i) * 64 + lane;
            const int r = u >> 4, cc = u & 15;
            const ushort* src = Kp + (size_t)(kt * 64 + r) * 128 + ((cc ^ (r & 15)) * 8);
            gld16(src, Kl + (w * 4 + i) * 1024);
        }
        const ushort* tile = Vp + (size_t)kt * 8192;
#pragma unroll
        for (int i = 0; i < 4; ++i) {
            const int u = (w * 4 + i) * 64 + lane;
            const int r = u >> 3, cc = u & 7;
            const ushort* src = tile + r * 64 + ((cc ^ (r & 7)) * 8);
            gld16(src, Vl + (w * 4 + i) * 1024);
        }
    };

    // ---- prologue: stage first K tile into buf0, overlap Q-frag loads ----
    stageK64(0, 0);

    bf16x8 qf[4];
    {
        const float* qptr = Qbh + (size_t)qme * RS_;
#pragma unroll
        for (int db = 0; db < 4; ++db) {
            const float* p = qptr + db * 32 + g * 8;
            f32x4 a = *(const f32x4*)p;
            f32x4 d = *(const f32x4*)(p + 4);
#pragma unroll
            for (int i = 0; i < 4; ++i) {
                qf[db][i]     = (short)f2bf(a[i] * QSC);
                qf[db][i + 4] = (short)f2bf(d[i] * QSC);
            }
        }
    }
    asm volatile("s_waitcnt vmcnt(0)" ::: "memory");
    __syncthreads();

    // ---- phase 1: l-sums + per-64-tile row maxima, BK=64, double-buffered ----
    float acc = 0.f;
    const int ktN = qt + 1;
    int cur = 0;
#pragma unroll 1
    for (int kt = 0; kt < ktN; ++kt) {
        if (kt + 1 < ktN) stageK64(kt + 1, cur ^ 1);   // prefetch before compute
        const ushort* K1 = (const ushort*)(SHc + cur * 16384);
        f32x4 s[4];
#pragma unroll
        for (int cb = 0; cb < 4; ++cb) s[cb] = (f32x4){0.f, 0.f, 0.f, 0.f};
        __builtin_amdgcn_s_setprio(1);
#pragma unroll
        for (int db = 0; db < 4; ++db) {
            const int usw = ((db * 4 + g) ^ l15) * 8;
#pragma unroll
            for (int cb = 0; cb < 4; ++cb) {
                bf16x8 kf = *(const bf16x8*)(K1 + (cb * 16 + l15) * 128 + usw);
                s[cb] = __builtin_amdgcn_mfma_f32_16x16x32_bf16(kf, qf[db], s[cb], 0, 0, 0);
            }
        }
        __builtin_amdgcn_s_setprio(0);

        float sm = -1e30f;
        if (kt == ktN - 1) {        // diagonal tile: causal mask
#pragma unroll
            for (int cb = 0; cb < 4; ++cb) {
                const int key0 = kt * 64 + cb * 16 + g * 4;
#pragma unroll
                for (int r = 0; r < 4; ++r) {
                    const bool ok = (key0 + r <= qme);
                    const float e = exp2f(s[cb][r]);
                    acc += ok ? e : 0.f;
                    sm = fmaxf(sm, ok ? s[cb][r] : -1e30f);
                }
            }
        } else {
#pragma unroll
            for (int cb = 0; cb < 4; ++cb)
#pragma unroll
                for (int r = 0; r < 4; ++r) {
                    acc += exp2f(s[cb][r]);
                    sm = fmaxf(sm, s[cb][r]);
                }
        }
        // reduce row max over the 4 g-groups; lanes 0..15 store
        sm = fmaxf(sm, __shfl_xor(sm, 16));
        sm = fmaxf(sm, __shfl_xor(sm, 32));
        if (lane < 16) SmaxL[(w * 32 + kt) * 16 + l15] = sm;
        asm volatile("s_waitcnt vmcnt(0)" ::: "memory");   // prefetch landed
        __syncthreads();
        cur ^= 1;
    }

    // ---- l-reduction, threshold, block-uniform active-tile mask (64-granular) ----
    float c1;
    {
        float t = acc;
        t += __shfl_xor(t, 16);
        t += __shfl_xor(t, 32);
        c1 = ZG / t;
    }
    const float thr = log2f(-GM / c1);   // s <= thr  =>  p clips to exactly 0

    uint mymask = 0;
#pragma unroll 1
    for (int st = 0; st < ktN; ++st) {
        const float sm = SmaxL[(w * 32 + st) * 16 + l15];
        if (__any(sm > thr)) mymask |= (1u << st);
    }
    if (lane == 0) Flags[w] = mymask;
    __syncthreads();
    const uint blockmask = Flags[0] | Flags[1] | Flags[2] | Flags[3];

    const int kt2 = qt + 1;
    int kt = 0;
    while (kt < kt2 && !((blockmask >> kt) & 1u)) ++kt;
    if (kt < kt2) stageKV(kt);
    asm volatile("s_waitcnt vmcnt(0)" ::: "memory");
    __syncthreads();

    // ---- phase 2: only active 64-tiles; P = clip(c1*e+GM), O += P V ----
    f32x4 o[8];
#pragma unroll
    for (int db = 0; db < 8; ++db) o[db] = (f32x4){0.f, 0.f, 0.f, 0.f};

#pragma unroll 1
    while (kt < kt2) {
        f32x4 s[4];
#pragma unroll
        for (int cb = 0; cb < 4; ++cb) s[cb] = (f32x4){0.f, 0.f, 0.f, 0.f};
        __builtin_amdgcn_s_setprio(1);
#pragma unroll
        for (int db = 0; db < 4; ++db) {
            const int usw = ((db * 4 + g) ^ l15) * 8;
#pragma unroll
            for (int cb = 0; cb < 4; ++cb) {
                bf16x8 kf = *(const bf16x8*)((const ushort*)Kl + (cb * 16 + l15) * 128 + usw);
                s[cb] = __builtin_amdgcn_mfma_f32_16x16x32_bf16(kf, qf[db], s[cb], 0, 0, 0);
            }
        }
        __builtin_amdgcn_s_setprio(0);

        // per-wave fine vote (rows of this wave only)
        float smax = fmaxf(fmaxf(fmaxf(s[0][0], s[0][1]), fmaxf(s[0][2], s[0][3])),
                           fmaxf(fmaxf(s[1][0], s[1][1]), fmaxf(s[1][2], s[1][3])));
        smax = fmaxf(smax,
               fmaxf(fmaxf(fmaxf(s[2][0], s[2][1]), fmaxf(s[2][2], s[2][3])),
                     fmaxf(fmaxf(s[3][0], s[3][1]), fmaxf(s[3][2], s[3][3]))));

        if (__any(smax > thr)) {
            const bool diag = (kt == kt2 - 1);
#pragma unroll
            for (int cb = 0; cb < 4; ++cb) {
                const int key0 = kt * 64 + cb * 16 + g * 4;
                float p[4];
#pragma unroll
                for (int r = 0; r < 4; ++r) {
                    float e = exp2f(s[cb][r]);
                    if (diag) e = (key0 + r <= qme) ? e : 0.f;
                    p[r] = fminf(fmaxf(c1 * e + GM, 0.f), 1.f);
                }
                uint r01, r23;
                asm("v_cvt_pk_bf16_f32 %0, %1, %2" : "=v"(r01) : "v"(p[0]), "v"(p[1]));
                asm("v_cvt_pk_bf16_f32 %0, %1, %2" : "=v"(r23) : "v"(p[2]), "v"(p[3]));
                i32x2 pv2 = {(int)r01, (int)r23};
                *(i32x2*)(pB + l15 * 144 + cb * 32 + g * 8) = pv2;   // keys cb*16+g*4..+3
            }
            // in-wave: P writes must land before cross-lane P reads
            asm volatile("s_waitcnt lgkmcnt(0)" ::: "memory");
            f32x4 onew[8];
            __builtin_amdgcn_s_setprio(1);
#pragma unroll
            for (int ks = 0; ks < 2; ++ks) {
                bf16x8 pf = *(const bf16x8*)(pB + l15 * 144 + ks * 64 + g * 16);
#pragma unroll
                for (int db = 0; db < 8; ++db) {
                    const int d = db * 16 + l15;
                    bf16x8 vf = *(const bf16x8*)(Vl + d * 128 +
                                                 (((ks * 4 + g) ^ (d & 7)) * 16));
                    f32x4& dst = (ks == 0) ? onew[db] : o[db];
                    const f32x4 src = (ks == 0) ? o[db] : onew[db];
                    dst = __builtin_amdgcn_mfma_f32_16x16x32_bf16(pf, vf, src, 0, 0, 0);
                }
            }
            __builtin_amdgcn_s_setprio(0);
        }

        // advance to next active 64-tile (block-uniform)
        int nkt = kt + 1;
        while (nkt < kt2 && !((blockmask >> nkt) & 1u)) ++nkt;
        __syncthreads();
        if (nkt < kt2) {
            stageKV(nkt);
            asm volatile("s_waitcnt vmcnt(0)" ::: "memory");
        }
        __syncthreads();
        kt = nkt;
    }

    // ---- epilogue: fp32 out ----
    const size_t orow0 = ((size_t)(b * S_ + qw0) * H_ + h) * D_;
#pragma unroll
    for (int db = 0; db < 8; ++db) {
#pragma unroll
        for (int r = 0; r < 4; ++r) {
            const int qr = g * 4 + r;
            Og[orow0 + (size_t)qr * RS_ + db * 16 + l15] = o[db][r];
        }
    }
}

// ---------------- fallback (round-4, no workspace needed) ----------------
__global__ __launch_bounds__(256, 2)
void attn_fwd(const float* __restrict__ Qg, const float* __restrict__ Kg,
              const float* __restrict__ Vg, float* __restrict__ Og)
{
    __shared__ ushort Kl[32 * 128];
    __shared__ ushort Vt[128 * 40];
    __shared__ ushort Pl[4][16 * 40];

    const int tid  = threadIdx.x;
    const int w    = tid >> 6;
    const int lane = tid & 63;
    const int g    = lane >> 4;
    const int l15  = lane & 15;

    const int q0 = blockIdx.x * 64;
    const int bh = blockIdx.y;
    const int b  = bh >> 4;
    const int h  = bh & (H_ - 1);

    const size_t bh_off = ((size_t)b * S_ * H_ + h) * D_;
    const float* Qp = Qg + bh_off;
    const float* Kp = Kg + bh_off;
    const float* Vp = Vg + bh_off;

    const int qw0 = q0 + w * 16;
    const int wave_last_q = qw0 + 15;
    bf16x8 qf[4];
    {
        const float* qptr = Qp + (size_t)(qw0 + l15) * RS_;
        const float sc = 0.08838834764831845f;
#pragma unroll
        for (int db = 0; db < 4; ++db) {
            const float* p = qptr + db * 32 + g * 8;
            f32x4 a = *(const f32x4*)p;
            f32x4 c = *(const f32x4*)(p + 4);
#pragma unroll
            for (int i = 0; i < 4; ++i) {
                qf[db][i]     = (short)f2bf(a[i] * sc);
                qf[db][i + 4] = (short)f2bf(c[i] * sc);
            }
        }
    }

    char* const klB = (char*)Kl;
    char* const vtB = (char*)Vt;
    const int kr  = tid >> 3;
    const int kcu = (tid & 7) * 2;
    const int vk  = (tid >> 5) * 4;
    const int vd  = (tid & 31) * 4;

    auto stageK = [&](int kt0) {
        const float* p = Kp + (size_t)(kt0 + kr) * RS_ + kcu * 8;
        f32x4 x0 = *(const f32x4*)(p);
        f32x4 x1 = *(const f32x4*)(p + 4);
        f32x4 x2 = *(const f32x4*)(p + 8);
        f32x4 x3 = *(const f32x4*)(p + 12);
        union { ushort u[8]; i32x4 v; } a, c;
#pragma unroll
        for (int i = 0; i < 4; ++i) {
            a.u[i]     = f2bf(x0[i]);
            a.u[i + 4] = f2bf(x1[i]);
            c.u[i]     = f2bf(x2[i]);
            c.u[i + 4] = f2bf(x3[i]);
        }
        const int sw = kr & 7;
        *(i32x4*)(klB + kr * 256 + ((kcu ^ sw) * 16))       = a.v;
        *(i32x4*)(klB + kr * 256 + (((kcu + 1) ^ sw) * 16)) = c.v;
    };

    auto stageV = [&](int kt0) {
        ushort t[4][4];
#pragma unroll
        for (int i = 0; i < 4; ++i) {
            const f32x4 x = *(const f32x4*)(Vp + (size_t)(kt0 + vk + i) * RS_ + vd);
#pragma unroll
            for (int j = 0; j < 4; ++j) t[i][j] = f2bf(x[j]);
        }
#pragma unroll
        for (int j = 0; j < 4; ++j) {
            union { ushort u[4]; i32x2 v; } pk;
#pragma unroll
            for (int i = 0; i < 4; ++i) pk.u[i] = t[i][j];
            *(i32x2*)(vtB + (size_t)(vd + j) * 80 + vk * 2) = pk.v;
        }
    };

    auto qkTile = [&](f32x4& s0, f32x4& s1) {
        s0 = (f32x4){0.f, 0.f, 0.f, 0.f};
        s1 = (f32x4){0.f, 0.f, 0.f, 0.f};
        const int swz = l15 & 7;
#pragma unroll
        for (int db = 0; db < 4; ++db) {
            const int unit = db * 4 + g;
            bf16x8 k0 = *(const bf16x8*)(klB + l15 * 256 + ((unit ^ swz) * 16));
            bf16x8 k1 = *(const bf16x8*)(klB + (l15 + 16) * 256 + ((unit ^ swz) * 16));
            s0 = __builtin_amdgcn_mfma_f32_16x16x32_bf16(qf[db], k0, s0, 0, 0, 0);
            s1 = __builtin_amdgcn_mfma_f32_16x16x32_bf16(qf[db], k1, s1, 0, 0, 0);
        }
    };

    const int ktiles = (q0 + 64) / 32;

    float m[4] = {-1e30f, -1e30f, -1e30f, -1e30f};
    float l[4] = {0.f, 0.f, 0.f, 0.f};

    for (int kt = 0; kt < ktiles; ++kt) {
        const int kt0 = kt * 32;
        __syncthreads();
        stageK(kt0);
        __syncthreads();
        if (kt0 > wave_last_q) continue;
        f32x4 s0, s1;
        qkTile(s0, s1);
#pragma unroll
        for (int r = 0; r < 4; ++r) {
            const int qq = qw0 + g * 4 + r;
            const int ke = kt0 + l15;
            float v0 = (ke <= qq)      ? s0[r] : -1e30f;
            float v1 = (ke + 16 <= qq) ? s1[r] : -1e30f;
            float tmax = fmaxf(v0, v1);
            tmax = fmaxf(tmax, __shfl_xor(tmax, 1));
            tmax = fmaxf(tmax, __shfl_xor(tmax, 2));
            tmax = fmaxf(tmax, __shfl_xor(tmax, 4));
            tmax = fmaxf(tmax, __shfl_xor(tmax, 8));
            const float mn = fmaxf(m[r], tmax);
            float es = exp2f((v0 - mn) * LOG2E) + exp2f((v1 - mn) * LOG2E);
            es += __shfl_xor(es, 1);
            es += __shfl_xor(es, 2);
            es += __shfl_xor(es, 4);
            es += __shfl_xor(es, 8);
            l[r] = l[r] * exp2f((m[r] - mn) * LOG2E) + es;
            m[r] = mn;
        }
    }

    float c1[4];
#pragma unroll
    for (int r = 0; r < 4; ++r) c1[r] = ZG / l[r];

    f32x4 o[8];
#pragma unroll
    for (int db = 0; db < 8; ++db) o[db] = (f32x4){0.f, 0.f, 0.f, 0.f};

    char* const pB = (char*)(Pl[w]);

    for (int kt = 0; kt < ktiles; ++kt) {
        const int kt0 = kt * 32;
        __syncthreads();
        stageK(kt0);
        stageV(kt0);
        __syncthreads();
        if (kt0 > wave_last_q) continue;
        f32x4 s0, s1;
        qkTile(s0, s1);
#pragma unroll
        for (int r = 0; r < 4; ++r) {
            const int qq = qw0 + g * 4 + r;
            const int ke = kt0 + l15;
            float v0 = (ke <= qq)      ? s0[r] : -1e30f;
            float v1 = (ke + 16 <= qq) ? s1[r] : -1e30f;
            float p0 = c1[r] * exp2f((v0 - m[r]) * LOG2E) + GM;
            float p1 = c1[r] * exp2f((v1 - m[r]) * LOG2E) + GM;
            p0 = fminf(fmaxf(p0, 0.f), 1.f);
            p1 = fminf(fmaxf(p1, 0.f), 1.f);
            const int qr = g * 4 + r;
            *(ushort*)(pB + qr * 80 + l15 * 2)        = f2bf(p0);
            *(ushort*)(pB + qr * 80 + (l15 + 16) * 2) = f2bf(p1);
        }
        asm volatile("s_waitcnt lgkmcnt(0)" ::: "memory");
        bf16x8 pf = *(const bf16x8*)(pB + l15 * 80 + g * 16);
#pragma unroll
        for (int db = 0; db < 8; ++db) {
            bf16x8 vf = *(const bf16x8*)(vtB + (size_t)(db * 16 + l15) * 80 + g * 16);
            o[db] = __builtin_amdgcn_mfma_f32_16x16x32_bf16(pf, vf, o[db], 0, 0, 0);
        }
    }

    const size_t orow0 = ((size_t)(b * S_ + qw0) * H_ + h) * D_;
#pragma unroll
    for (int db = 0; db < 8; ++db) {
#pragma unroll
        for (int r = 0; r < 4; ++r) {
            const int qr = g * 4 + r;
            Og[orow0 + (size_t)qr * RS_ + db * 16 + l15] = o[db][r];
        }
    }
}

extern "C" void kernel_launch(void* const* d_in, const int* in_sizes, int n_in,
                              void* d_out, int out_size, void* d_ws, size_t ws_size,
                              hipStream_t stream)
{
    const float* Q = (const float*)d_in[0];
    const float* K = (const float*)d_in[1];
    const float* V = (const float*)d_in[2];
    (void)in_sizes; (void)n_in; (void)out_size;

    if (ws_size >= (size_t)33554432) {
        ushort* Kb = (ushort*)d_ws;
        ushort* Vt = (ushort*)d_ws + 8388608;   // +16 MB
        prep_kv<<<dim3(1536), dim3(256), 0, stream>>>(K, V, Kb, Vt);
        attn_one<<<dim3(1024), dim3(256), 0, stream>>>(Q, Kb, Vt, (float*)d_out);
    } else {
        attn_fwd<<<dim3(S_ / 64, B_ * H_), dim3(256), 0, stream>>>(Q, K, V, (float*)d_out);
    }
}

// Round 21
// 83.019 us; speedup vs baseline: 1.3924x; 1.0031x over previous
//
#include <hip/hip_runtime.h>

typedef __attribute__((ext_vector_type(4))) float f32x4;
typedef __attribute__((ext_vector_type(8))) short bf16x8;
typedef __attribute__((ext_vector_type(4))) int   i32x4;
typedef __attribute__((ext_vector_type(2))) int   i32x2;

#define B_ 2
#define S_ 2048
#define H_ 16
#define D_ 128
#define RS_ (H_ * D_)
#define LOG2E 1.44269504088896340736f
#define ZG 1.06f               // zeta - gamma
#define GM (-0.03f)            // gamma
#define QSC (0.08838834764831845f * LOG2E)   // 1/sqrt(128)*log2(e) folded into Q

__device__ __forceinline__ ushort f2bf(float x) {
    uint u = __builtin_bit_cast(uint, x);
    u += 0x7FFFu + ((u >> 16) & 1u);
    return (ushort)(u >> 16);
}

__device__ __forceinline__ void gld16(const void* g, void* l) {
    __builtin_amdgcn_global_load_lds(
        (const __attribute__((address_space(1))) unsigned int*)g,
        (__attribute__((address_space(3))) unsigned int*)l, 16, 0, 0);
}

// ---- fused prep: n<512 -> K fp32 -> bf16 [bh][s][d]; n>=512 -> V -> V^T tiles ----
__global__ __launch_bounds__(256)
void prep_kv(const float* __restrict__ Kg, const float* __restrict__ Vg,
             ushort* __restrict__ Kb, ushort* __restrict__ Vt)
{
    __shared__ ushort Vl[64 * 136];     // only used on the V path
    const int t = threadIdx.x;
    if (blockIdx.x < 512) {
        const int n  = blockIdx.x;      // K path: 512 blocks
        const int bh = n >> 4;
        const int ch = n & 15;
        const int s  = ch * 128 + (t >> 1);
        const int d0 = (t & 1) * 64;
        const int b  = bh >> 4, h = bh & 15;
        const float* in = Kg + (((size_t)b * S_ + s) * H_ + h) * D_ + d0;
        ushort* out = Kb + ((size_t)bh * S_ + s) * D_ + d0;
#pragma unroll
        for (int j = 0; j < 4; ++j) {
            f32x4 x0 = *(const f32x4*)(in + j * 16);
            f32x4 x1 = *(const f32x4*)(in + j * 16 + 4);
            f32x4 x2 = *(const f32x4*)(in + j * 16 + 8);
            f32x4 x3 = *(const f32x4*)(in + j * 16 + 12);
            union { ushort u[16]; i32x4 v[2]; } p;
#pragma unroll
            for (int i = 0; i < 4; ++i) {
                p.u[i]      = f2bf(x0[i]);
                p.u[4 + i]  = f2bf(x1[i]);
                p.u[8 + i]  = f2bf(x2[i]);
                p.u[12 + i] = f2bf(x3[i]);
            }
            *(i32x4*)(out + j * 16)     = p.v[0];
            *(i32x4*)(out + j * 16 + 8) = p.v[1];
        }
    } else {
        const int n  = blockIdx.x - 512;    // V path: 1024 blocks
        const int bh = n >> 5;
        const int kt = n & 31;
        const int b  = bh >> 4, h = bh & 15;
#pragma unroll
        for (int it = 0; it < 2; ++it) {
            const int r  = it * 32 + (t >> 3);
            const int c0 = (t & 7) * 16;
            const int s  = kt * 64 + r;
            const float* in = Vg + (((size_t)b * S_ + s) * H_ + h) * D_ + c0;
            f32x4 x0 = *(const f32x4*)(in);
            f32x4 x1 = *(const f32x4*)(in + 4);
            f32x4 x2 = *(const f32x4*)(in + 8);
            f32x4 x3 = *(const f32x4*)(in + 12);
            union { ushort u[16]; i32x4 v[2]; } p;
#pragma unroll
            for (int i = 0; i < 4; ++i) {
                p.u[i]      = f2bf(x0[i]);
                p.u[4 + i]  = f2bf(x1[i]);
                p.u[8 + i]  = f2bf(x2[i]);
                p.u[12 + i] = f2bf(x3[i]);
            }
            *(i32x4*)(Vl + r * 136 + c0)     = p.v[0];
            *(i32x4*)(Vl + r * 136 + c0 + 8) = p.v[1];
        }
        __syncthreads();
        const int d  = t >> 1;
        const int kh = (t & 1) * 32;
        ushort* out = Vt + ((size_t)bh * 32 + kt) * 8192 + d * 64 + kh;
        uint wds[16];
#pragma unroll
        for (int i = 0; i < 16; ++i) {
            uint a = Vl[(kh + 2 * i) * 136 + d];
            uint c = Vl[(kh + 2 * i + 1) * 136 + d];
            wds[i] = a | (c << 16);
        }
#pragma unroll
        for (int j = 0; j < 4; ++j)
            *(i32x4*)(out + j * 8) = *(i32x4*)&wds[j * 4];
    }
}

// ---- fused single-strip, swapped-QK, fine-grained tile-skip phase 2 ----
// Phase 1: BK=64, K double-buffered (prefetch before compute); l-accumulation
// split into 4 independent chains (cuts the 16-deep fp32 add dependency 4x).
// Per-64-tile row maxima -> block-uniform skip mask; phase 2 only active tiles.
__global__ __launch_bounds__(256, 3)
void attn_one(const float* __restrict__ Qg, const ushort* __restrict__ Kb,
              const ushort* __restrict__ Vt, float* __restrict__ Og)
{
    __shared__ char SHc[32768 + 4 * 2304 + 8192 + 16];

    const int tid  = threadIdx.x;
    const int w    = tid >> 6;
    const int lane = tid & 63;
    const int g    = lane >> 4;
    const int l15  = lane & 15;
    char*  const Kl    = SHc;                      // phase2 K / phase1 buf0
    char*  const Vl    = SHc + 16384;              // phase2 V / phase1 buf1
    char*  const pB    = SHc + 32768 + w * 2304;   // per-wave P [16 q][64 k], 144B rows
    float* const SmaxL = (float*)(SHc + 41984);    // [w][kt(0..31)][l15]
    uint*  const Flags = (uint*)(SHc + 50176);     // [w]

    const int n  = blockIdx.x;                 // 1024 blocks
    const int qt = 31 - (n >> 5);              // big strips dispatch first (LPT)
    const int bh = n & 31;
    const int b  = bh >> 4, h = bh & 15;

    const int q0  = qt * 64;
    const int qw0 = q0 + w * 16;
    const int qme = qw0 + l15;                 // this lane's q row

    const float*  Qbh = Qg + ((size_t)b * S_ * H_ + h) * D_;
    const ushort* Kp  = Kb + (size_t)bh * S_ * D_;
    const ushort* Vp  = Vt + (size_t)bh * 32 * 8192;

    auto stageK64 = [&](int kt, int bset) {  // 16 KB: K rows kt*64..+63, 16-slot swz
#pragma unroll
        for (int i = 0; i < 4; ++i) {
            const int u = (w * 4 + i) * 64 + lane;
            const int r = u >> 4, cc = u & 15;
            const ushort* src = Kp + (size_t)(kt * 64 + r) * 128 + ((cc ^ (r & 15)) * 8);
            gld16(src, SHc + bset * 16384 + (w * 4 + i) * 1024);
        }
    };
    auto stageKV = [&](int kt) {     // 16 KB K (16-slot swz) + 16 KB V^T (8-slot swz)
#pragma unroll
        for (int i = 0; i < 4; ++i) {
            const int u = (w * 4 + i) * 64 + lane;
            const int r = u >> 4, cc = u & 15;
            const ushort* src = Kp + (size_t)(kt * 64 + r) * 128 + ((cc ^ (r & 15)) * 8);
            gld16(src, Kl + (w * 4 + i) * 1024);
        }
        const ushort* tile = Vp + (size_t)kt * 8192;
#pragma unroll
        for (int i = 0; i < 4; ++i) {
            const int u = (w * 4 + i) * 64 + lane;
            const int r = u >> 3, cc = u & 7;
            const ushort* src = tile + r * 64 + ((cc ^ (r & 7)) * 8);
            gld16(src, Vl + (w * 4 + i) * 1024);
        }
    };

    // ---- prologue: stage first K tile into buf0, overlap Q-frag loads ----
    stageK64(0, 0);

    bf16x8 qf[4];
    {
        const float* qptr = Qbh + (size_t)qme * RS_;
#pragma unroll
        for (int db = 0; db < 4; ++db) {
            const float* p = qptr + db * 32 + g * 8;
            f32x4 a = *(const f32x4*)p;
            f32x4 d = *(const f32x4*)(p + 4);
#pragma unroll
            for (int i = 0; i < 4; ++i) {
                qf[db][i]     = (short)f2bf(a[i] * QSC);
                qf[db][i + 4] = (short)f2bf(d[i] * QSC);
            }
        }
    }
    asm volatile("s_waitcnt vmcnt(0)" ::: "memory");
    __syncthreads();

    // ---- phase 1: l-sums + per-64-tile row maxima, BK=64, double-buffered ----
    float acc4[4] = {0.f, 0.f, 0.f, 0.f};      // 4 independent add chains
    const int ktN = qt + 1;
    int cur = 0;
#pragma unroll 1
    for (int kt = 0; kt < ktN; ++kt) {
        if (kt + 1 < ktN) stageK64(kt + 1, cur ^ 1);   // prefetch before compute
        const ushort* K1 = (const ushort*)(SHc + cur * 16384);
        f32x4 s[4];
#pragma unroll
        for (int cb = 0; cb < 4; ++cb) s[cb] = (f32x4){0.f, 0.f, 0.f, 0.f};
        __builtin_amdgcn_s_setprio(1);
#pragma unroll
        for (int db = 0; db < 4; ++db) {
            const int usw = ((db * 4 + g) ^ l15) * 8;
#pragma unroll
            for (int cb = 0; cb < 4; ++cb) {
                bf16x8 kf = *(const bf16x8*)(K1 + (cb * 16 + l15) * 128 + usw);
                s[cb] = __builtin_amdgcn_mfma_f32_16x16x32_bf16(kf, qf[db], s[cb], 0, 0, 0);
            }
        }
        __builtin_amdgcn_s_setprio(0);

        float sm = -1e30f;
        if (kt == ktN - 1) {        // diagonal tile: causal mask
#pragma unroll
            for (int cb = 0; cb < 4; ++cb) {
                const int key0 = kt * 64 + cb * 16 + g * 4;
#pragma unroll
                for (int r = 0; r < 4; ++r) {
                    const bool ok = (key0 + r <= qme);
                    const float e = exp2f(s[cb][r]);
                    acc4[cb] += ok ? e : 0.f;
                    sm = fmaxf(sm, ok ? s[cb][r] : -1e30f);
                }
            }
        } else {
#pragma unroll
            for (int cb = 0; cb < 4; ++cb)
#pragma unroll
                for (int r = 0; r < 4; ++r) {
                    acc4[cb] += exp2f(s[cb][r]);
                    sm = fmaxf(sm, s[cb][r]);
                }
        }
        // reduce row max over the 4 g-groups; lanes 0..15 store
        sm = fmaxf(sm, __shfl_xor(sm, 16));
        sm = fmaxf(sm, __shfl_xor(sm, 32));
        if (lane < 16) SmaxL[(w * 32 + kt) * 16 + l15] = sm;
        asm volatile("s_waitcnt vmcnt(0)" ::: "memory");   // prefetch landed
        __syncthreads();
        cur ^= 1;
    }

    // ---- l-reduction, threshold, block-uniform active-tile mask (64-granular) ----
    float c1;
    {
        float t = (acc4[0] + acc4[1]) + (acc4[2] + acc4[3]);
        t += __shfl_xor(t, 16);
        t += __shfl_xor(t, 32);
        c1 = ZG / t;
    }
    const float thr = log2f(-GM / c1);   // s <= thr  =>  p clips to exactly 0

    uint mymask = 0;
#pragma unroll 1
    for (int st = 0; st < ktN; ++st) {
        const float sm = SmaxL[(w * 32 + st) * 16 + l15];
        if (__any(sm > thr)) mymask |= (1u << st);
    }
    if (lane == 0) Flags[w] = mymask;
    __syncthreads();
    const uint blockmask = Flags[0] | Flags[1] | Flags[2] | Flags[3];

    const int kt2 = qt + 1;
    int kt = 0;
    while (kt < kt2 && !((blockmask >> kt) & 1u)) ++kt;
    if (kt < kt2) stageKV(kt);
    asm volatile("s_waitcnt vmcnt(0)" ::: "memory");
    __syncthreads();

    // ---- phase 2: only active 64-tiles; P = clip(c1*e+GM), O += P V ----
    f32x4 o[8];
#pragma unroll
    for (int db = 0; db < 8; ++db) o[db] = (f32x4){0.f, 0.f, 0.f, 0.f};

#pragma unroll 1
    while (kt < kt2) {
        f32x4 s[4];
#pragma unroll
        for (int cb = 0; cb < 4; ++cb) s[cb] = (f32x4){0.f, 0.f, 0.f, 0.f};
        __builtin_amdgcn_s_setprio(1);
#pragma unroll
        for (int db = 0; db < 4; ++db) {
            const int usw = ((db * 4 + g) ^ l15) * 8;
#pragma unroll
            for (int cb = 0; cb < 4; ++cb) {
                bf16x8 kf = *(const bf16x8*)((const ushort*)Kl + (cb * 16 + l15) * 128 + usw);
                s[cb] = __builtin_amdgcn_mfma_f32_16x16x32_bf16(kf, qf[db], s[cb], 0, 0, 0);
            }
        }
        __builtin_amdgcn_s_setprio(0);

        // per-wave fine vote (rows of this wave only)
        float smax = fmaxf(fmaxf(fmaxf(s[0][0], s[0][1]), fmaxf(s[0][2], s[0][3])),
                           fmaxf(fmaxf(s[1][0], s[1][1]), fmaxf(s[1][2], s[1][3])));
        smax = fmaxf(smax,
               fmaxf(fmaxf(fmaxf(s[2][0], s[2][1]), fmaxf(s[2][2], s[2][3])),
                     fmaxf(fmaxf(s[3][0], s[3][1]), fmaxf(s[3][2], s[3][3]))));

        if (__any(smax > thr)) {
            const bool diag = (kt == kt2 - 1);
#pragma unroll
            for (int cb = 0; cb < 4; ++cb) {
                const int key0 = kt * 64 + cb * 16 + g * 4;
                float p[4];
#pragma unroll
                for (int r = 0; r < 4; ++r) {
                    float e = exp2f(s[cb][r]);
                    if (diag) e = (key0 + r <= qme) ? e : 0.f;
                    p[r] = fminf(fmaxf(c1 * e + GM, 0.f), 1.f);
                }
                uint r01, r23;
                asm("v_cvt_pk_bf16_f32 %0, %1, %2" : "=v"(r01) : "v"(p[0]), "v"(p[1]));
                asm("v_cvt_pk_bf16_f32 %0, %1, %2" : "=v"(r23) : "v"(p[2]), "v"(p[3]));
                i32x2 pv2 = {(int)r01, (int)r23};
                *(i32x2*)(pB + l15 * 144 + cb * 32 + g * 8) = pv2;   // keys cb*16+g*4..+3
            }
            // in-wave: P writes must land before cross-lane P reads
            asm volatile("s_waitcnt lgkmcnt(0)" ::: "memory");
            f32x4 onew[8];
            __builtin_amdgcn_s_setprio(1);
#pragma unroll
            for (int ks = 0; ks < 2; ++ks) {
                bf16x8 pf = *(const bf16x8*)(pB + l15 * 144 + ks * 64 + g * 16);
#pragma unroll
                for (int db = 0; db < 8; ++db) {
                    const int d = db * 16 + l15;
                    bf16x8 vf = *(const bf16x8*)(Vl + d * 128 +
                                                 (((ks * 4 + g) ^ (d & 7)) * 16));
                    f32x4& dst = (ks == 0) ? onew[db] : o[db];
                    const f32x4 src = (ks == 0) ? o[db] : onew[db];
                    dst = __builtin_amdgcn_mfma_f32_16x16x32_bf16(pf, vf, src, 0, 0, 0);
                }
            }
            __builtin_amdgcn_s_setprio(0);
        }

        // advance to next active 64-tile (block-uniform)
        int nkt = kt + 1;
        while (nkt < kt2 && !((blockmask >> nkt) & 1u)) ++nkt;
        __syncthreads();
        if (nkt < kt2) {
            stageKV(nkt);
            asm volatile("s_waitcnt vmcnt(0)" ::: "memory");
        }
        __syncthreads();
        kt = nkt;
    }

    // ---- epilogue: fp32 out ----
    const size_t orow0 = ((size_t)(b * S_ + qw0) * H_ + h) * D_;
#pragma unroll
    for (int db = 0; db < 8; ++db) {
#pragma unroll
        for (int r = 0; r < 4; ++r) {
            const int qr = g * 4 + r;
            Og[orow0 + (size_t)qr * RS_ + db * 16 + l15] = o[db][r];
        }
    }
}

// ---------------- fallback (round-4, no workspace needed) ----------------
__global__ __launch_bounds__(256, 2)
void attn_fwd(const float* __restrict__ Qg, const float* __restrict__ Kg,
              const float* __restrict__ Vg, float* __restrict__ Og)
{
    __shared__ ushort Kl[32 * 128];
    __shared__ ushort Vt[128 * 40];
    __shared__ ushort Pl[4][16 * 40];

    const int tid  = threadIdx.x;
    const int w    = tid >> 6;
    const int lane = tid & 63;
    const int g    = lane >> 4;
    const int l15  = lane & 15;

    const int q0 = blockIdx.x * 64;
    const int bh = blockIdx.y;
    const int b  = bh >> 4;
    const int h  = bh & (H_ - 1);

    const size_t bh_off = ((size_t)b * S_ * H_ + h) * D_;
    const float* Qp = Qg + bh_off;
    const float* Kp = Kg + bh_off;
    const float* Vp = Vg + bh_off;

    const int qw0 = q0 + w * 16;
    const int wave_last_q = qw0 + 15;
    bf16x8 qf[4];
    {
        const float* qptr = Qp + (size_t)(qw0 + l15) * RS_;
        const float sc = 0.08838834764831845f;
#pragma unroll
        for (int db = 0; db < 4; ++db) {
            const float* p = qptr + db * 32 + g * 8;
            f32x4 a = *(const f32x4*)p;
            f32x4 c = *(const f32x4*)(p + 4);
#pragma unroll
            for (int i = 0; i < 4; ++i) {
                qf[db][i]     = (short)f2bf(a[i] * sc);
                qf[db][i + 4] = (short)f2bf(c[i] * sc);
            }
        }
    }

    char* const klB = (char*)Kl;
    char* const vtB = (char*)Vt;
    const int kr  = tid >> 3;
    const int kcu = (tid & 7) * 2;
    const int vk  = (tid >> 5) * 4;
    const int vd  = (tid & 31) * 4;

    auto stageK = [&](int kt0) {
        const float* p = Kp + (size_t)(kt0 + kr) * RS_ + kcu * 8;
        f32x4 x0 = *(const f32x4*)(p);
        f32x4 x1 = *(const f32x4*)(p + 4);
        f32x4 x2 = *(const f32x4*)(p + 8);
        f32x4 x3 = *(const f32x4*)(p + 12);
        union { ushort u[8]; i32x4 v; } a, c;
#pragma unroll
        for (int i = 0; i < 4; ++i) {
            a.u[i]     = f2bf(x0[i]);
            a.u[i + 4] = f2bf(x1[i]);
            c.u[i]     = f2bf(x2[i]);
            c.u[i + 4] = f2bf(x3[i]);
        }
        const int sw = kr & 7;
        *(i32x4*)(klB + kr * 256 + ((kcu ^ sw) * 16))       = a.v;
        *(i32x4*)(klB + kr * 256 + (((kcu + 1) ^ sw) * 16)) = c.v;
    };

    auto stageV = [&](int kt0) {
        ushort t[4][4];
#pragma unroll
        for (int i = 0; i < 4; ++i) {
            const f32x4 x = *(const f32x4*)(Vp + (size_t)(kt0 + vk + i) * RS_ + vd);
#pragma unroll
            for (int j = 0; j < 4; ++j) t[i][j] = f2bf(x[j]);
        }
#pragma unroll
        for (int j = 0; j < 4; ++j) {
            union { ushort u[4]; i32x2 v; } pk;
#pragma unroll
            for (int i = 0; i < 4; ++i) pk.u[i] = t[i][j];
            *(i32x2*)(vtB + (size_t)(vd + j) * 80 + vk * 2) = pk.v;
        }
    };

    auto qkTile = [&](f32x4& s0, f32x4& s1) {
        s0 = (f32x4){0.f, 0.f, 0.f, 0.f};
        s1 = (f32x4){0.f, 0.f, 0.f, 0.f};
        const int swz = l15 & 7;
#pragma unroll
        for (int db = 0; db < 4; ++db) {
            const int unit = db * 4 + g;
            bf16x8 k0 = *(const bf16x8*)(klB + l15 * 256 + ((unit ^ swz) * 16));
            bf16x8 k1 = *(const bf16x8*)(klB + (l15 + 16) * 256 + ((unit ^ swz) * 16));
            s0 = __builtin_amdgcn_mfma_f32_16x16x32_bf16(qf[db], k0, s0, 0, 0, 0);
            s1 = __builtin_amdgcn_mfma_f32_16x16x32_bf16(qf[db], k1, s1, 0, 0, 0);
        }
    };

    const int ktiles = (q0 + 64) / 32;

    float m[4] = {-1e30f, -1e30f, -1e30f, -1e30f};
    float l[4] = {0.f, 0.f, 0.f, 0.f};

    for (int kt = 0; kt < ktiles; ++kt) {
        const int kt0 = kt * 32;
        __syncthreads();
        stageK(kt0);
        __syncthreads();
        if (kt0 > wave_last_q) continue;
        f32x4 s0, s1;
        qkTile(s0, s1);
#pragma unroll
        for (int r = 0; r < 4; ++r) {
            const int qq = qw0 + g * 4 + r;
            const int ke = kt0 + l15;
            float v0 = (ke <= qq)      ? s0[r] : -1e30f;
            float v1 = (ke + 16 <= qq) ? s1[r] : -1e30f;
            float tmax = fmaxf(v0, v1);
            tmax = fmaxf(tmax, __shfl_xor(tmax, 1));
            tmax = fmaxf(tmax, __shfl_xor(tmax, 2));
            tmax = fmaxf(tmax, __shfl_xor(tmax, 4));
            tmax = fmaxf(tmax, __shfl_xor(tmax, 8));
            const float mn = fmaxf(m[r], tmax);
            float es = exp2f((v0 - mn) * LOG2E) + exp2f((v1 - mn) * LOG2E);
            es += __shfl_xor(es, 1);
            es += __shfl_xor(es, 2);
            es += __shfl_xor(es, 4);
            es += __shfl_xor(es, 8);
            l[r] = l[r] * exp2f((m[r] - mn) * LOG2E) + es;
            m[r] = mn;
        }
    }

    float c1[4];
#pragma unroll
    for (int r = 0; r < 4; ++r) c1[r] = ZG / l[r];

    f32x4 o[8];
#pragma unroll
    for (int db = 0; db < 8; ++db) o[db] = (f32x4){0.f, 0.f, 0.f, 0.f};

    char* const pB = (char*)(Pl[w]);

    for (int kt = 0; kt < ktiles; ++kt) {
        const int kt0 = kt * 32;
        __syncthreads();
        stageK(kt0);
        stageV(kt0);
        __syncthreads();
        if (kt0 > wave_last_q) continue;
        f32x4 s0, s1;
        qkTile(s0, s1);
#pragma unroll
        for (int r = 0; r < 4; ++r) {
            const int qq = qw0 + g * 4 + r;
            const int ke = kt0 + l15;
            float v0 = (ke <= qq)      ? s0[r] : -1e30f;
            float v1 = (ke + 16 <= qq) ? s1[r] : -1e30f;
            float p0 = c1[r] * exp2f((v0 - m[r]) * LOG2E) + GM;
            float p1 = c1[r] * exp2f((v1 - m[r]) * LOG2E) + GM;
            p0 = fminf(fmaxf(p0, 0.f), 1.f);
            p1 = fminf(fmaxf(p1, 0.f), 1.f);
            const int qr = g * 4 + r;
            *(ushort*)(pB + qr * 80 + l15 * 2)        = f2bf(p0);
            *(ushort*)(pB + qr * 80 + (l15 + 16) * 2) = f2bf(p1);
        }
        asm volatile("s_waitcnt lgkmcnt(0)" ::: "memory");
        bf16x8 pf = *(const bf16x8*)(pB + l15 * 80 + g * 16);
#pragma unroll
        for (int db = 0; db < 8; ++db) {
            bf16x8 vf = *(const bf16x8*)(vtB + (size_t)(db * 16 + l15) * 80 + g * 16);
            o[db] = __builtin_amdgcn_mfma_f32_16x16x32_bf16(pf, vf, o[db], 0, 0, 0);
        }
    }

    const size_t orow0 = ((size_t)(b * S_ + qw0) * H_ + h) * D_;
#pragma unroll
    for (int db = 0; db < 8; ++db) {
#pragma unroll
        for (int r = 0; r < 4; ++r) {
            const int qr = g * 4 + r;
            Og[orow0 + (size_t)qr * RS_ + db * 16 + l15] = o[db][r];
        }
    }
}

extern "C" void kernel_launch(void* const* d_in, const int* in_sizes, int n_in,
                              void* d_out, int out_size, void* d_ws, size_t ws_size,
                              hipStream_t stream)
{
    const float* Q = (const float*)d_in[0];
    const float* K = (const float*)d_in[1];
    const float* V = (const float*)d_in[2];
    (void)in_sizes; (void)n_in; (void)out_size;

    if (ws_size >= (size_t)33554432) {
        ushort* Kb = (ushort*)d_ws;
        ushort* Vt = (ushort*)d_ws + 8388608;   // +16 MB
        prep_kv<<<dim3(1536), dim3(256), 0, stream>>>(K, V, Kb, Vt);
        attn_one<<<dim3(1024), dim3(256), 0, stream>>>(Q, Kb, Vt, (float*)d_out);
    } else {
        attn_fwd<<<dim3(S_ / 64, B_ * H_), dim3(256), 0, stream>>>(Q, K, V, (float*)d_out);
    }
}